// Round 1
// baseline (3167.122 us; speedup 1.0000x reference)
//
#include <hip/hip_runtime.h>
#include <cstdint>
#include <cstddef>

// ============================================================================
// EfficientMemoryHadamard: result = x1*x2 ; out_i = quantile(|x_i|,0.99) ;
// R_i / Rinv_i from randomized SVD (rank 16, 2 power iters) of the residual.
//
// Assumption stack (flip these in future rounds if R outputs fail):
//  A1: jax threefry_partitionable=True (foldlike split, bits = o0^o1, ctr=(0,i))
//  A2: jnp quantile index = f32(0.99)*f32(33554431) = 33218888.0 exactly (frac 0)
//  A3: CPU gesdd path: gelqf -> gebd2 -> bdsqr(lasdq) -> ormbr -> gemm
//  A4: LAPACK >= 3.10 slartg sign convention (c>=0, r=sign(d,f))
// ============================================================================

#define DEV __device__ __forceinline__

constexpr long long NTOT = 33554432LL;           // 4*2048*4096
constexpr unsigned long long KSEL = 33218888ULL; // 0-indexed order statistic

constexpr long long OUT_T1  = 33554432LL;
constexpr long long OUT_R1  = 33554433LL;
constexpr long long OUT_RI1 = 33619969LL;
constexpr long long OUT_T2  = 33685505LL;
constexpr long long OUT_R2  = 33685506LL;
constexpr long long OUT_RI2 = 33751042LL;

// ---- workspace layout (float units) ----
constexpr size_t OFF_FINE   = 0;          // 2 * 1048576 u32 (zeroed)
constexpr size_t OFF_COARSE = 2097152;    // 2 * 2048 u32    (zeroed)
constexpr size_t OFF_GRAM   = 2101248;    // 12 * 256        (zeroed)
constexpr size_t OFF_TBUF   = 2104320;    // 6 * 65536       (zeroed, atomic targets)
constexpr size_t ZERO_FLOATS= 2497536;
constexpr size_t OFF_SELR   = 2497536;    // 16 ints
constexpr size_t OFF_TSEL   = 2497552;    // 2 floats
constexpr size_t OFF_OMT    = 2497560;    // 2*65536  omega^T (16x4096)
constexpr size_t OFF_BIGY   = 2628632;    // 2*131072 (8192x16)
constexpr size_t OFF_BIGQ   = 2890776;    // 2*131072 (8192x16)
constexpr size_t OFF_ZT     = 3152920;    // 2*65536  Z^T (16x4096)
constexpr size_t OFF_QQR    = 3283992;    // 2*65536  Qqr (4096x16)
constexpr size_t OFF_S      = 3415064;    // 2*256
constexpr size_t OFF_QTOP   = 3415576;    // 2*256
constexpr size_t OFF_RG     = 3416088;    // 2*256
constexpr size_t OFF_VTL    = 3416600;    // 2*256
// total 3417112 floats ~= 13.7 MB

// ---------------------------------------------------------------------------
// Threefry-2x32 (20 rounds) — exact jax semantics
// ---------------------------------------------------------------------------
#define TFR(a,b,r) { a += b; b = (b << r) | (b >> (32 - r)); b ^= a; }

DEV void d_threefry(uint32_t k0, uint32_t k1, uint32_t x0, uint32_t x1,
                    uint32_t& o0, uint32_t& o1){
  uint32_t ks2 = k0 ^ k1 ^ 0x1BD11BDAu;
  x0 += k0; x1 += k1;
  TFR(x0,x1,13) TFR(x0,x1,15) TFR(x0,x1,26) TFR(x0,x1,6)
  x0 += k1; x1 += ks2 + 1u;
  TFR(x0,x1,17) TFR(x0,x1,29) TFR(x0,x1,16) TFR(x0,x1,24)
  x0 += ks2; x1 += k0 + 2u;
  TFR(x0,x1,13) TFR(x0,x1,15) TFR(x0,x1,26) TFR(x0,x1,6)
  x0 += k0; x1 += k1 + 3u;
  TFR(x0,x1,17) TFR(x0,x1,29) TFR(x0,x1,16) TFR(x0,x1,24)
  x0 += k1; x1 += ks2 + 4u;
  TFR(x0,x1,13) TFR(x0,x1,15) TFR(x0,x1,26) TFR(x0,x1,6)
  x0 += ks2; x1 += k0 + 5u;
  o0 = x0; o1 = x1;
}

static void h_threefry(uint32_t k0, uint32_t k1, uint32_t x0, uint32_t x1,
                       uint32_t& o0, uint32_t& o1){
  uint32_t ks2 = k0 ^ k1 ^ 0x1BD11BDAu;
  x0 += k0; x1 += k1;
  TFR(x0,x1,13) TFR(x0,x1,15) TFR(x0,x1,26) TFR(x0,x1,6)
  x0 += k1; x1 += ks2 + 1u;
  TFR(x0,x1,17) TFR(x0,x1,29) TFR(x0,x1,16) TFR(x0,x1,24)
  x0 += ks2; x1 += k0 + 2u;
  TFR(x0,x1,13) TFR(x0,x1,15) TFR(x0,x1,26) TFR(x0,x1,6)
  x0 += k0; x1 += k1 + 3u;
  TFR(x0,x1,17) TFR(x0,x1,29) TFR(x0,x1,16) TFR(x0,x1,24)
  x0 += k1; x1 += ks2 + 4u;
  TFR(x0,x1,13) TFR(x0,x1,15) TFR(x0,x1,26) TFR(x0,x1,6)
  x0 += ks2; x1 += k0 + 5u;
  o0 = x0; o1 = x1;
}

// XLA ErfInv (f32, Giles polynomial)
DEV float erfinv_f32(float x){
  float w = -log1pf(-x*x);
  float p;
  if (w < 5.0f){
    w -= 2.5f;
    p = 2.81022636e-08f;
    p = fmaf(p, w, 3.43273939e-07f);
    p = fmaf(p, w, -3.5233877e-06f);
    p = fmaf(p, w, -4.39150654e-06f);
    p = fmaf(p, w, 0.00021858087f);
    p = fmaf(p, w, -0.00125372503f);
    p = fmaf(p, w, -0.00417768164f);
    p = fmaf(p, w, 0.246640727f);
    p = fmaf(p, w, 1.50140941f);
  } else {
    w = sqrtf(w) - 3.0f;
    p = -0.000200214257f;
    p = fmaf(p, w, 0.000100950558f);
    p = fmaf(p, w, 0.00134934322f);
    p = fmaf(p, w, -0.00367342844f);
    p = fmaf(p, w, 0.00573950773f);
    p = fmaf(p, w, -0.0076224613f);
    p = fmaf(p, w, 0.00943887047f);
    p = fmaf(p, w, 1.00167406f);
    p = fmaf(p, w, 2.83297682f);
  }
  return p * x;
}

DEV float lapy2f(float x, float y){
  float xa = fabsf(x), ya = fabsf(y);
  float w = fmaxf(xa, ya), z = fminf(xa, ya);
  if (z == 0.f) return w;
  float q = z / w;
  return w * sqrtf(1.f + q*q);
}

// LAPACK 3.10+ slartg (fast path; magnitudes here never hit scaling branches)
DEV void slartg_(float f, float g, float& c, float& s, float& r){
  if (g == 0.f){ c = 1.f; s = 0.f; r = f; }
  else if (f == 0.f){ c = 0.f; s = copysignf(1.f, g); r = fabsf(g); }
  else {
    float d = sqrtf(f*f + g*g);
    c = fabsf(f) / d;
    r = copysignf(d, f);
    s = g / r;
  }
}

DEV void slas2_(float f, float g, float h, float& ssmin, float& ssmax){
  float fa = fabsf(f), ga = fabsf(g), ha = fabsf(h);
  float fhmn = fminf(fa, ha), fhmx = fmaxf(fa, ha);
  if (fhmn == 0.f){
    ssmin = 0.f;
    if (fhmx == 0.f) ssmax = ga;
    else {
      float mx = fmaxf(fhmx, ga), mn = fminf(fhmx, ga);
      float q = mn/mx;
      ssmax = mx*sqrtf(1.f + q*q);
    }
  } else {
    if (ga < fhmx){
      float as_ = 1.f + fhmn/fhmx;
      float at_ = (fhmx - fhmn)/fhmx;
      float au = ga/fhmx; au = au*au;
      float cc = 2.f/(sqrtf(as_*as_ + au) + sqrtf(at_*at_ + au));
      ssmin = fhmn*cc; ssmax = fhmx/cc;
    } else {
      float au = fhmx/ga;
      if (au == 0.f){ ssmin = (fhmn*fhmx)/ga; ssmax = ga; }
      else {
        float as_ = 1.f + fhmn/fhmx;
        float at_ = (fhmx - fhmn)/fhmx;
        float q1 = as_*au, q2 = at_*au;
        float cc = 1.f/(sqrtf(1.f + q1*q1) + sqrtf(1.f + q2*q2));
        ssmin = (fhmn*cc)*au; ssmin = ssmin + ssmin;
        ssmax = ga/(cc + cc);
      }
    }
  }
}

// LAPACK slasv2: args (F,G,H, SSMIN,SSMAX, SNR,CSR, SNL,CSL)
DEV void slasv2_(float f, float g, float h, float& ssmin, float& ssmax,
                 float& snr, float& csr, float& snl, float& csl){
  const float eps = 5.9604645e-08f;
  float ft = f, fa = fabsf(f), ht = h, ha = fabsf(h);
  int pmax = 1;
  bool swp = (ha > fa);
  if (swp){ pmax = 3; float t; t=ft; ft=ht; ht=t; t=fa; fa=ha; ha=t; }
  float gt = g, ga = fabsf(g);
  float clt = 0.f, crt = 0.f, slt = 0.f, srt = 0.f;
  if (ga == 0.f){ ssmin = ha; ssmax = fa; clt = 1.f; crt = 1.f; slt = 0.f; srt = 0.f; }
  else {
    bool gasmal = true;
    if (ga > fa){
      pmax = 2;
      if ((fa/ga) < eps){
        gasmal = false;
        ssmax = ga;
        if (ha > 1.f) ssmin = fa/(ga/ha); else ssmin = (fa/ga)*ha;
        clt = 1.f; slt = ht/gt; srt = 1.f; crt = ft/gt;
      }
    }
    if (gasmal){
      float dd = fa - ha;
      float L = (dd == fa) ? 1.f : dd/fa;
      float Mv = gt/ft;
      float T = 2.f - L;
      float MM = Mv*Mv, TT = T*T;
      float Sv = sqrtf(TT + MM);
      float Rv = (L == 0.f) ? fabsf(Mv) : sqrtf(L*L + MM);
      float Av = 0.5f*(Sv + Rv);
      ssmin = ha/Av; ssmax = fa*Av;
      float Tv;
      if (MM == 0.f){
        if (L == 0.f) Tv = copysignf(2.f, ft)*copysignf(1.f, gt);
        else Tv = gt/copysignf(dd, ft) + Mv/T;
      } else {
        Tv = (Mv/(Sv + T) + Mv/(Rv + L))*(1.f + Av);
      }
      float Lv = sqrtf(Tv*Tv + 4.f);
      crt = 2.f/Lv; srt = Tv/Lv;
      clt = (crt + srt*Mv)/Av;
      slt = (ht/ft)*srt/Av;
    }
  }
  if (swp){ csl = srt; snl = crt; csr = slt; snr = clt; }
  else    { csl = clt; snl = slt; csr = crt; snr = srt; }
  float tsign = 1.f;
  if (pmax == 1) tsign = copysignf(1.f, csr)*copysignf(1.f, csl)*copysignf(1.f, f);
  if (pmax == 2) tsign = copysignf(1.f, snr)*copysignf(1.f, csl)*copysignf(1.f, g);
  if (pmax == 3) tsign = copysignf(1.f, snr)*copysignf(1.f, snl)*copysignf(1.f, h);
  ssmax = copysignf(ssmax, tsign);
  ssmin = copysignf(ssmin, tsign*copysignf(1.f, f)*copysignf(1.f, h));
}

// ===========================================================================
// K1: out = x1*x2 fused with coarse 12-bit |x| histograms for both tensors
// ===========================================================================
__global__ __launch_bounds__(256) void k_hadamard_hist(const float* __restrict__ x1,
    const float* __restrict__ x2, float* __restrict__ out, float* __restrict__ ws){
  __shared__ uint32_t lh[2][2048];
  for (int i = threadIdx.x; i < 4096; i += 256) (&lh[0][0])[i] = 0u;
  __syncthreads();
  uint32_t* h1 = (uint32_t*)(ws + OFF_COARSE);
  uint32_t* h2 = h1 + 2048;
  const float4* a4 = (const float4*)x1;
  const float4* b4 = (const float4*)x2;
  float4* o4 = (float4*)out;
  long long n4 = NTOT/4;
  long long stride = (long long)gridDim.x * 256;
  for (long long i = (long long)blockIdx.x*256 + threadIdx.x; i < n4; i += stride){
    float4 a = a4[i], b = b4[i];
    float4 o; o.x=a.x*b.x; o.y=a.y*b.y; o.z=a.z*b.z; o.w=a.w*b.w;
    o4[i] = o;
    atomicAdd(&lh[0][(__float_as_uint(a.x)&0x7fffffffu)>>20], 1u);
    atomicAdd(&lh[0][(__float_as_uint(a.y)&0x7fffffffu)>>20], 1u);
    atomicAdd(&lh[0][(__float_as_uint(a.z)&0x7fffffffu)>>20], 1u);
    atomicAdd(&lh[0][(__float_as_uint(a.w)&0x7fffffffu)>>20], 1u);
    atomicAdd(&lh[1][(__float_as_uint(b.x)&0x7fffffffu)>>20], 1u);
    atomicAdd(&lh[1][(__float_as_uint(b.y)&0x7fffffffu)>>20], 1u);
    atomicAdd(&lh[1][(__float_as_uint(b.z)&0x7fffffffu)>>20], 1u);
    atomicAdd(&lh[1][(__float_as_uint(b.w)&0x7fffffffu)>>20], 1u);
  }
  __syncthreads();
  for (int i = threadIdx.x; i < 2048; i += 256){
    uint32_t c0 = lh[0][i]; if (c0) atomicAdd(&h1[i], c0);
    uint32_t c1 = lh[1][i]; if (c1) atomicAdd(&h2[i], c1);
  }
}

// K2: scan coarse histogram -> (coarse bin, rank within bin)
__global__ __launch_bounds__(256) void k_coarse_scan(float* __restrict__ ws){
  int ty = blockIdx.x;
  const uint32_t* h = (const uint32_t*)(ws + OFF_COARSE) + ty*2048;
  int* selr = (int*)(ws + OFF_SELR) + ty*4;
  __shared__ unsigned long long ps[256];
  unsigned long long s = 0;
  for (int j = 0; j < 8; j++) s += h[threadIdx.x*8 + j];
  ps[threadIdx.x] = s;
  __syncthreads();
  if (threadIdx.x == 0){
    unsigned long long cum = 0, K = KSEL;
    int g = 0;
    for (; g < 256; g++){ if (cum + ps[g] > K) break; cum += ps[g]; }
    if (g > 255) g = 255;
    int bin = 2047;
    for (int j = 0; j < 8; j++){
      uint32_t c = h[g*8 + j];
      if (cum + c > K){ bin = g*8 + j; break; }
      cum += c;
    }
    selr[0] = bin;
    selr[1] = (int)(K - cum);
  }
}

// K3: fine 20-bit histogram inside the selected coarse bin
__global__ __launch_bounds__(256) void k_fine_hist(const float* __restrict__ x1,
    const float* __restrict__ x2, float* __restrict__ ws){
  int ty = blockIdx.y;
  const float4* x4 = (const float4*)(ty ? x2 : x1);
  const int* selr = (const int*)(ws + OFF_SELR) + ty*4;
  uint32_t bin = (uint32_t)selr[0];
  uint32_t* f = (uint32_t*)(ws + OFF_FINE) + (size_t)ty*1048576;
  long long n4 = NTOT/4;
  long long stride = (long long)gridDim.x * 256;
  for (long long i = (long long)blockIdx.x*256 + threadIdx.x; i < n4; i += stride){
    float4 a = x4[i];
    uint32_t u;
    u = __float_as_uint(a.x)&0x7fffffffu; if ((u>>20)==bin) atomicAdd(&f[u&0xFFFFFu],1u);
    u = __float_as_uint(a.y)&0x7fffffffu; if ((u>>20)==bin) atomicAdd(&f[u&0xFFFFFu],1u);
    u = __float_as_uint(a.z)&0x7fffffffu; if ((u>>20)==bin) atomicAdd(&f[u&0xFFFFFu],1u);
    u = __float_as_uint(a.w)&0x7fffffffu; if ((u>>20)==bin) atomicAdd(&f[u&0xFFFFFu],1u);
  }
}

// K4: scan fine histogram -> exact order-statistic bit pattern = threshold t
__global__ __launch_bounds__(1024) void k_fine_scan(float* __restrict__ ws, float* __restrict__ out){
  int ty = blockIdx.x;
  const uint32_t* f = (const uint32_t*)(ws + OFF_FINE) + (size_t)ty*1048576;
  const int* selr = (const int*)(ws + OFF_SELR) + ty*4;
  __shared__ unsigned long long ps[1024];
  unsigned long long s = 0;
  int base = threadIdx.x*1024;
  for (int j = 0; j < 1024; j++) s += f[base + j];
  ps[threadIdx.x] = s;
  __syncthreads();
  if (threadIdx.x == 0){
    unsigned long long K = (unsigned long long)(unsigned int)selr[1];
    unsigned long long cum = 0;
    int g = 0;
    for (; g < 1024; g++){ if (cum + ps[g] > K) break; cum += ps[g]; }
    if (g > 1023) g = 1023;
    int fineIdx = 1023 + g*1024;
    for (int j = 0; j < 1024; j++){
      uint32_t c = f[g*1024 + j];
      if (cum + c > K){ fineIdx = g*1024 + j; break; }
      cum += c;
    }
    uint32_t bits = (((uint32_t)selr[0])<<20) | (uint32_t)(fineIdx & 0xFFFFF);
    float t = __uint_as_float(bits);
    ws[OFF_TSEL + ty] = t;
    out[ty ? OUT_T2 : OUT_T1] = t;
  }
}

// K5: omega^T via threefry (partitionable path: bits = o0^o1, ctr=(0, flat_idx))
__global__ __launch_bounds__(256) void k_omega(uint32_t a0, uint32_t a1,
    uint32_t b0, uint32_t b1, float* __restrict__ ws){
  int ty = blockIdx.y;
  uint32_t k0 = ty ? b0 : a0, k1 = ty ? b1 : a1;
  int i = blockIdx.x*256 + threadIdx.x;    // flat index over (4096,16)
  uint32_t o0, o1;
  d_threefry(k0, k1, 0u, (uint32_t)i, o0, o1);
  uint32_t bits = o0 ^ o1;
  float fr = __uint_as_float((bits >> 9) | 0x3f800000u) - 1.0f;
  const float lo = -0.99999994f;           // nextafter(-1,0) in f32
  float u = fr * 2.0f + lo;
  u = fmaxf(lo, u);
  float v = 1.41421356237f * erfinv_f32(u);
  int row = i >> 4, col = i & 15;
  ws[OFF_OMT + (size_t)ty*65536 + (size_t)col*4096 + row] = v;
}

// K6: A-type matmul  Y(8192x16) = residual(x) * W   (W given as W^T 16x4096)
//     fused gram(Y) excluding top-16 rows (atomic into gram slot)
__global__ __launch_bounds__(256) void k_atype(const float* __restrict__ x1,
    const float* __restrict__ x2, float* __restrict__ ws, size_t wtOff, int gslot){
  int ty = blockIdx.y;
  const float* x = ty ? x2 : x1;
  const float* wt = ws + wtOff + (size_t)ty*65536;
  float* Y = ws + OFF_BIGY + (size_t)ty*131072;
  float* G = ws + OFF_GRAM + (size_t)(ty*6 + gslot)*256;
  float t = ws[OFF_TSEL + ty];
  int wave = threadIdx.x >> 6, lane = threadIdx.x & 63;
  __shared__ __align__(16) float wts[16][256];
  __shared__ float outs[16][16];
  float acc[4][16];
  #pragma unroll
  for (int r = 0; r < 4; r++)
    #pragma unroll
    for (int j = 0; j < 16; j++) acc[r][j] = 0.f;
  int rowbase = blockIdx.x*16 + wave*4;
  for (int c = 0; c < 4096; c += 256){
    __syncthreads();
    for (int idx = threadIdx.x; idx < 16*64; idx += 256){
      int j = idx >> 6, q = idx & 63;
      ((float4*)&wts[j][0])[q] = ((const float4*)(wt + (size_t)j*4096 + c))[q];
    }
    __syncthreads();
    for (int rr = 0; rr < 4; rr++){
      int row = rowbase + rr;
      float4 xv = ((const float4*)(x + (size_t)row*4096 + c))[lane];
      xv.x = fabsf(xv.x) > t ? 0.f : xv.x;
      xv.y = fabsf(xv.y) > t ? 0.f : xv.y;
      xv.z = fabsf(xv.z) > t ? 0.f : xv.z;
      xv.w = fabsf(xv.w) > t ? 0.f : xv.w;
      #pragma unroll
      for (int j = 0; j < 16; j++){
        float4 w4 = ((const float4*)&wts[j][0])[lane];
        acc[rr][j] = fmaf(xv.x, w4.x, acc[rr][j]);
        acc[rr][j] = fmaf(xv.y, w4.y, acc[rr][j]);
        acc[rr][j] = fmaf(xv.z, w4.z, acc[rr][j]);
        acc[rr][j] = fmaf(xv.w, w4.w, acc[rr][j]);
      }
    }
  }
  #pragma unroll
  for (int rr = 0; rr < 4; rr++)
    for (int j = 0; j < 16; j++){
      float v = acc[rr][j];
      for (int off = 32; off > 0; off >>= 1) v += __shfl_xor(v, off, 64);
      if (lane == 0) outs[wave*4 + rr][j] = v;
    }
  __syncthreads();
  int r = threadIdx.x >> 4, cc = threadIdx.x & 15;
  float val = outs[r][cc];
  Y[(size_t)(blockIdx.x*16 + r)*16 + cc] = val;
  if (blockIdx.x > 0){
    float gs = 0.f;
    for (int rrow = 0; rrow < 16; rrow++) gs += outs[rrow][r]*outs[rrow][cc];
    atomicAdd(&G[r*16 + cc], gs);
  }
}

// K7: B-type matmul  T(4096x16) += residual(x)^T * Q(8192x16)   (atomic)
__global__ __launch_bounds__(256) void k_btype(const float* __restrict__ x1,
    const float* __restrict__ x2, float* __restrict__ ws, int tslot){
  int ty = blockIdx.y;
  const float* x = ty ? x2 : x1;
  const float* Q = ws + OFF_BIGQ + (size_t)ty*131072;
  float* T = ws + OFF_TBUF + (size_t)(ty*3 + tslot)*65536;
  float t = ws[OFF_TSEL + ty];
  int cc = blockIdx.x >> 6;   // 0..3 column chunk (1024 cols)
  int rc = blockIdx.x & 63;   // 0..63 row chunk (128 rows)
  int c0 = cc*1024 + threadIdx.x;
  int r0 = rc*128;
  __shared__ __align__(16) float Qs[64][16];
  float acc[4][16];
  #pragma unroll
  for (int a = 0; a < 4; a++)
    #pragma unroll
    for (int j = 0; j < 16; j++) acc[a][j] = 0.f;
  for (int rchunk = 0; rchunk < 128; rchunk += 64){
    __syncthreads();
    ((float4*)&Qs[0][0])[threadIdx.x] =
        ((const float4*)(Q + (size_t)(r0 + rchunk)*16))[threadIdx.x];
    __syncthreads();
    for (int rr = 0; rr < 64; rr++){
      int row = r0 + rchunk + rr;
      const float* xr = x + (size_t)row*4096;
      float v0 = xr[c0];       v0 = fabsf(v0) > t ? 0.f : v0;
      float v1 = xr[c0+256];   v1 = fabsf(v1) > t ? 0.f : v1;
      float v2 = xr[c0+512];   v2 = fabsf(v2) > t ? 0.f : v2;
      float v3 = xr[c0+768];   v3 = fabsf(v3) > t ? 0.f : v3;
      #pragma unroll
      for (int j = 0; j < 16; j++){
        float qv = Qs[rr][j];
        acc[0][j] = fmaf(v0, qv, acc[0][j]);
        acc[1][j] = fmaf(v1, qv, acc[1][j]);
        acc[2][j] = fmaf(v2, qv, acc[2][j]);
        acc[3][j] = fmaf(v3, qv, acc[3][j]);
      }
    }
  }
  for (int a = 0; a < 4; a++){
    int c = c0 + a*256;
    for (int j = 0; j < 16; j++) atomicAdd(&T[(size_t)c*16 + j], acc[a][j]);
  }
}

// K8: gram of a 4096x16 matrix (skip top-16 rows), atomic into gram slot
__global__ __launch_bounds__(256) void k_gram(float* __restrict__ ws, int tslot, int gslot){
  int ty = blockIdx.y;
  const float* T = ws + OFF_TBUF + (size_t)(ty*3 + tslot)*65536;
  float* G = ws + OFF_GRAM + (size_t)(ty*6 + gslot)*256;
  __shared__ __align__(16) float buf[128][16];
  int t = threadIdx.x;
  for (int q = t; q < 512; q += 256)
    ((float4*)&buf[0][0])[q] = ((const float4*)(T + (size_t)blockIdx.x*2048))[q];
  __syncthreads();
  int i = t >> 4, j = t & 15;
  float s = 0.f;
  int rstart = (blockIdx.x == 0) ? 16 : 0;
  for (int r = rstart; r < 128; r++) s += buf[r][i]*buf[r][j];
  atomicAdd(&G[i*16 + j], s);
}

// K9: tiny per-QR kernel. chol(G)=R_B; C=[M_top;R_B]; LAPACK geqrf+org2r on C;
//     S = R_B^{-1} Q_bot; outputs S, Q_top, R_g. One wave per tensor.
__global__ __launch_bounds__(64) void k_tiny(float* __restrict__ ws, size_t mOff,
    size_t mStr, int gslot){
  int ty = blockIdx.x;
  const float* Mp = ws + mOff + (size_t)ty*mStr;
  float* g = ws + OFF_GRAM + (size_t)(ty*6 + gslot)*256;
  float* sOut = ws + OFF_S + ty*256;
  float* qtOut = ws + OFF_QTOP + ty*256;
  float* rgOut = ws + OFF_RG + ty*256;
  __shared__ float G[16][16];
  __shared__ float C[32][16];
  __shared__ float Qs[32][16];
  __shared__ float S[16][16];
  __shared__ float tau[16];
  int l = threadIdx.x;
  for (int idx = l; idx < 256; idx += 64) G[idx>>4][idx&15] = g[idx];
  __syncthreads();
  // cholesky (upper) in place
  for (int k = 0; k < 16; k++){
    float dk = sqrtf(G[k][k]);
    if (l == k) G[k][k] = dk;
    else if (l > k && l < 16) G[k][l] = G[k][l] / dk;
    __syncthreads();
    if (l > k && l < 16)
      for (int j = l; j < 16; j++) G[l][j] -= G[k][l]*G[k][j];
    __syncthreads();
  }
  // C = [M_top ; R_B]
  for (int idx = l; idx < 512; idx += 64){
    int r = idx >> 4, c = idx & 15;
    float v;
    if (r < 16) v = Mp[r*16 + c];
    else v = (c >= r - 16) ? G[r-16][c] : 0.f;
    C[r][c] = v;
  }
  __syncthreads();
  // LAPACK-convention geqrf on 32x16 C
  for (int i = 0; i < 16; i++){
    float alpha = C[i][i];
    float ssum = 0.f;
    for (int r = i+1; r < 32; r++) ssum += C[r][i]*C[r][i];
    float xn = sqrtf(ssum);
    float beta, tv;
    if (xn == 0.f){ tv = 0.f; beta = alpha; }
    else {
      beta = -copysignf(lapy2f(alpha, xn), alpha);
      tv = (beta - alpha)/beta;
      float sc = 1.f/(alpha - beta);
      if (l > i && l < 32) C[l][i] *= sc;
    }
    if (l == 0){ C[i][i] = beta; tau[i] = tv; }
    __syncthreads();
    if (tv != 0.f && l > i && l < 16){
      int j = l;
      float w = C[i][j];
      for (int r = i+1; r < 32; r++) w += C[r][i]*C[r][j];
      w *= tv;
      C[i][j] -= w;
      for (int r = i+1; r < 32; r++) C[r][j] -= w*C[r][i];
    }
    __syncthreads();
  }
  for (int idx = l; idx < 256; idx += 64){
    int r = idx >> 4, c = idx & 15;
    rgOut[idx] = (c >= r) ? C[r][c] : 0.f;
  }
  // org2r
  for (int idx = l; idx < 512; idx += 64) Qs[idx>>4][idx&15] = 0.f;
  __syncthreads();
  for (int i = 15; i >= 0; i--){
    float tv = tau[i];
    if (i < 15 && l > i && l < 16){
      int j = l;
      float w = Qs[i][j];
      for (int r = i+1; r < 32; r++) w += C[r][i]*Qs[r][j];
      w *= tv;
      Qs[i][j] -= w;
      for (int r = i+1; r < 32; r++) Qs[r][j] -= w*C[r][i];
    }
    __syncthreads();
    if (l > i && l < 32) Qs[l][i] = -tv * C[l][i];
    if (l == i) Qs[i][i] = 1.f - tv;
    if (l < i) Qs[l][i] = 0.f;
    __syncthreads();
  }
  // back-solve S = R_B^{-1} * Qs[16:32]
  if (l < 16){
    int j = l;
    for (int i2 = 15; i2 >= 0; i2--){
      float v = Qs[16 + i2][j];
      for (int k2 = i2+1; k2 < 16; k2++) v -= G[i2][k2]*S[k2][j];
      S[i2][j] = v / G[i2][i2];
    }
  }
  __syncthreads();
  for (int idx = l; idx < 256; idx += 64){
    sOut[idx] = S[idx>>4][idx&15];
    qtOut[idx] = Qs[idx>>4][idx&15];
  }
}

// K10: Q = [Q_top ; M(17:,:)*S]  (optionally also transposed layout 16 x 4096)
__global__ __launch_bounds__(256) void k_applyq(float* __restrict__ ws, size_t mOff,
    size_t mStr, size_t oOff, size_t oStr, int nrows, int wN, int wT){
  int ty = blockIdx.y;
  const float* Mp = ws + mOff + (size_t)ty*mStr;
  const float* sP = ws + OFF_S + ty*256;
  const float* qtP = ws + OFF_QTOP + ty*256;
  float* oP = ws + oOff + (size_t)ty*oStr;
  __shared__ float Ss[16][16], Qt[16][16];
  int t = threadIdx.x;
  Ss[t>>4][t&15] = sP[t];
  Qt[t>>4][t&15] = qtP[t];
  __syncthreads();
  int row = blockIdx.x*256 + t;
  if (row >= nrows) return;
  float o[16];
  if (row < 16){
    #pragma unroll
    for (int j = 0; j < 16; j++) o[j] = Qt[row][j];
  } else {
    float mv[16];
    #pragma unroll
    for (int q = 0; q < 4; q++){
      float4 v = ((const float4*)(Mp + (size_t)row*16))[q];
      mv[q*4] = v.x; mv[q*4+1] = v.y; mv[q*4+2] = v.z; mv[q*4+3] = v.w;
    }
    #pragma unroll
    for (int j = 0; j < 16; j++){
      float sacc = 0.f;
      #pragma unroll
      for (int i = 0; i < 16; i++) sacc = fmaf(mv[i], Ss[i][j], sacc);
      o[j] = sacc;
    }
  }
  if (wN){
    #pragma unroll
    for (int q = 0; q < 4; q++){
      float4 v; v.x = o[q*4]; v.y = o[q*4+1]; v.z = o[q*4+2]; v.w = o[q*4+3];
      ((float4*)(oP + (size_t)row*16))[q] = v;
    }
  }
  if (wT){
    #pragma unroll
    for (int j = 0; j < 16; j++) oP[(size_t)j*4096 + row] = o[j];
  }
}

// K11: the 16x16 gesdd tail: gebd2 -> bdsqr (VT only) -> ormbr('P','R','T')
#define Dv(i) d_[(i)-1]
#define Ev(i) e_[(i)-1]
__global__ __launch_bounds__(64) void k_chain(float* __restrict__ ws){
  int ty = blockIdx.x;
  const float* rg = ws + OFF_RG + ty*256;
  float* vtlOut = ws + OFF_VTL + ty*256;
  const int n = 16;
  __shared__ float A[16][16];
  __shared__ float VTm[16][16];
  __shared__ float d_[16], e_[16], tauq[16], taup[16];
  __shared__ float w1[16], w2[16], w3[16], w4[16];
  int l = threadIdx.x;
  for (int idx = l; idx < 256; idx += 64){
    int r = idx >> 4, c = idx & 15;
    A[r][c] = (r >= c) ? rg[c*16 + r] : 0.f;   // L = Rg^T
  }
  __syncthreads();
  // ---- gebd2 ----
  for (int i = 0; i < n; i++){
    {
      float alpha = A[i][i];
      float ssum = 0.f;
      for (int r = i+1; r < n; r++) ssum += A[r][i]*A[r][i];
      float xn = sqrtf(ssum);
      float beta, tv;
      if (n - i <= 1 || xn == 0.f){ tv = 0.f; beta = alpha; }
      else {
        beta = -copysignf(lapy2f(alpha, xn), alpha);
        tv = (beta - alpha)/beta;
        float sc = 1.f/(alpha - beta);
        if (l > i && l < n) A[l][i] *= sc;
      }
      if (l == 0){ d_[i] = beta; tauq[i] = tv; }
      __syncthreads();
      if (tv != 0.f && l > i && l < n){
        int j = l;
        float w = A[i][j];
        for (int r = i+1; r < n; r++) w += A[r][i]*A[r][j];
        w *= tv;
        A[i][j] -= w;
        for (int r = i+1; r < n; r++) A[r][j] -= w*A[r][i];
      }
      __syncthreads();
    }
    if (i < n-1){
      float alpha = A[i][i+1];
      float ssum = 0.f;
      for (int c = i+2; c < n; c++) ssum += A[i][c]*A[i][c];
      float xn = sqrtf(ssum);
      float beta, tp;
      if (n - i - 1 <= 1 || xn == 0.f){ tp = 0.f; beta = alpha; }
      else {
        beta = -copysignf(lapy2f(alpha, xn), alpha);
        tp = (beta - alpha)/beta;
        float sc = 1.f/(alpha - beta);
        if (l >= i+2 && l < n) A[i][l] *= sc;
      }
      if (l == 0){ e_[i] = beta; taup[i] = tp; }
      __syncthreads();
      if (tp != 0.f && l > i && l < n){
        int r = l;
        float w = A[r][i+1];
        for (int c = i+2; c < n; c++) w += A[i][c]*A[r][c];
        w *= tp;
        A[r][i+1] -= w;
        for (int c = i+2; c < n; c++) A[r][c] -= w*A[i][c];
      }
      __syncthreads();
    } else {
      if (l == 0) taup[i] = 0.f;
      __syncthreads();
    }
  }
  for (int idx = l; idx < 256; idx += 64){
    int r = idx >> 4, c = idx & 15;
    VTm[r][c] = (r == c) ? 1.f : 0.f;
  }
  __syncthreads();
  // ---- bdsqr ('U', ncvt=16, nru=0, ncc=0) ----
  const float eps = 5.9604645e-08f;
  const float unfl = 1.17549435e-38f;
  const float tol = 10.f*eps;       // tolmul = max(10, min(100, eps^-1/8)) = 10
  float sminoa = fabsf(Dv(1));
  if (sminoa != 0.f){
    float mu = sminoa;
    for (int i = 2; i <= n; i++){
      mu = fabsf(Dv(i))*(mu/(mu + fabsf(Ev(i-1))));
      sminoa = fminf(sminoa, mu);
      if (sminoa == 0.f) break;
    }
  }
  sminoa = sminoa / sqrtf((float)n);
  float thresh = fmaxf(tol*sminoa, (float)(6*n*n)*unfl);
  int maxit = 6*n*n;
  int iter = 0, oldll = -1, oldm = -1, mm = n, idir = 0;
  while (true){
    if (mm <= 1) break;
    if (iter > maxit) break;
    float smaxw = fabsf(Dv(mm));
    int llv = 0; bool split = false;
    for (int lll = 1; lll <= mm-1; lll++){
      llv = mm - lll;
      float abss = fabsf(Dv(llv));
      float abse = fabsf(Ev(llv));
      if (abse <= thresh){ split = true; break; }
      smaxw = fmaxf(smaxw, fmaxf(abss, abse));
    }
    if (split){
      Ev(llv) = 0.f;
      if (llv == mm-1){ mm = mm - 1; continue; }
      llv = llv + 1;
    } else llv = 1;
    if (llv == mm-1){
      float sigmn, sigmx, sinr, cosr, sinl, cosl;
      slasv2_(Dv(mm-1), Ev(mm-1), Dv(mm), sigmn, sigmx, sinr, cosr, sinl, cosl);
      Dv(mm-1) = sigmx; Ev(mm-1) = 0.f; Dv(mm) = sigmn;
      if (l < 16){
        float tA = VTm[mm-2][l], tB = VTm[mm-1][l];
        VTm[mm-2][l] = cosr*tA + sinr*tB;
        VTm[mm-1][l] = cosr*tB - sinr*tA;
      }
      mm -= 2;
      continue;
    }
    if (llv > oldm || mm < oldll)
      idir = (fabsf(Dv(llv)) >= fabsf(Dv(mm))) ? 1 : 2;
    bool deflated = false;
    float sminl = 0.f;
    if (idir == 1){
      if (fabsf(Ev(mm-1)) <= tol*fabsf(Dv(mm))){ Ev(mm-1) = 0.f; continue; }
      float mu = fabsf(Dv(llv)); sminl = mu;
      for (int lll = llv; lll <= mm-1; lll++){
        if (fabsf(Ev(lll)) <= tol*mu){ Ev(lll) = 0.f; deflated = true; break; }
        mu = fabsf(Dv(lll+1))*(mu/(mu + fabsf(Ev(lll))));
        sminl = fminf(sminl, mu);
      }
    } else {
      if (fabsf(Ev(llv)) <= tol*fabsf(Dv(llv))){ Ev(llv) = 0.f; continue; }
      float mu = fabsf(Dv(mm)); sminl = mu;
      for (int lll = mm-1; lll >= llv; lll--){
        if (fabsf(Ev(lll)) <= tol*mu){ Ev(lll) = 0.f; deflated = true; break; }
        mu = fabsf(Dv(lll))*(mu/(mu + fabsf(Ev(lll))));
        sminl = fminf(sminl, mu);
      }
    }
    if (deflated) continue;
    oldll = llv; oldm = mm;
    float shift = 0.f, rdum;
    if (!((float)n*tol*(sminl/smaxw) <= fmaxf(eps, 0.01f*tol))){
      float sll;
      if (idir == 1){ sll = fabsf(Dv(llv)); slas2_(Dv(mm-1), Ev(mm-1), Dv(mm), shift, rdum); }
      else          { sll = fabsf(Dv(mm));  slas2_(Dv(llv), Ev(llv), Dv(llv+1), shift, rdum); }
      if (sll > 0.f){ float q = shift/sll; if (q*q < eps) shift = 0.f; }
    }
    iter += mm - llv;
    if (shift == 0.f){
      if (idir == 1){
        float cs = 1.f, oldcs = 1.f, sn = 0.f, oldsn = 0.f, rr, dnew;
        for (int i = llv; i <= mm-1; i++){
          slartg_(Dv(i)*cs, Ev(i), cs, sn, rr);
          if (i > llv) Ev(i-1) = oldsn*rr;
          slartg_(oldcs*rr, Dv(i+1)*sn, oldcs, oldsn, dnew);
          Dv(i) = dnew;
          w1[i-llv] = cs; w2[i-llv] = sn;
        }
        float h = Dv(mm)*cs;
        Dv(mm) = h*oldcs;
        Ev(mm-1) = h*oldsn;
        if (l < 16){
          for (int j = 0; j < mm-llv; j++){
            float c = w1[j], s = w2[j];
            if (c != 1.f || s != 0.f){
              float tmp = VTm[llv+j][l];
              float t0  = VTm[llv+j-1][l];
              VTm[llv+j][l]   = c*tmp - s*t0;
              VTm[llv+j-1][l] = s*tmp + c*t0;
            }
          }
        }
        if (fabsf(Ev(mm-1)) <= thresh) Ev(mm-1) = 0.f;
      } else {
        float cs = 1.f, oldcs = 1.f, sn = 0.f, oldsn = 0.f, rr, dnew;
        for (int i = mm; i >= llv+1; i--){
          slartg_(Dv(i)*cs, Ev(i-1), cs, sn, rr);
          if (i < mm) Ev(i) = oldsn*rr;
          slartg_(oldcs*rr, Dv(i-1)*sn, oldcs, oldsn, dnew);
          Dv(i) = dnew;
          w3[i-llv-1] = oldcs; w4[i-llv-1] = -oldsn;
        }
        float h = Dv(llv)*cs;
        Dv(llv) = h*oldcs;
        Ev(llv) = h*oldsn;
        if (l < 16){
          for (int j = mm-llv-1; j >= 0; j--){
            float c = w3[j], s = w4[j];
            if (c != 1.f || s != 0.f){
              float tmp = VTm[llv+j][l];
              float t0  = VTm[llv+j-1][l];
              VTm[llv+j][l]   = c*tmp - s*t0;
              VTm[llv+j-1][l] = s*tmp + c*t0;
            }
          }
        }
        if (fabsf(Ev(llv)) <= thresh) Ev(llv) = 0.f;
      }
    } else {
      if (idir == 1){
        float ff = (fabsf(Dv(llv)) - shift)*(copysignf(1.f, Dv(llv)) + shift/Dv(llv));
        float gg = Ev(llv);
        float cosr, sinr, cosl, sinl, rr;
        for (int i = llv; i <= mm-1; i++){
          slartg_(ff, gg, cosr, sinr, rr);
          if (i > llv) Ev(i-1) = rr;
          ff = cosr*Dv(i) + sinr*Ev(i);
          Ev(i) = cosr*Ev(i) - sinr*Dv(i);
          gg = sinr*Dv(i+1);
          Dv(i+1) = cosr*Dv(i+1);
          slartg_(ff, gg, cosl, sinl, rr);
          Dv(i) = rr;
          ff = cosl*Ev(i) + sinl*Dv(i+1);
          Dv(i+1) = cosl*Dv(i+1) - sinl*Ev(i);
          if (i < mm-1){
            gg = sinl*Ev(i+1);
            Ev(i+1) = cosl*Ev(i+1);
          }
          w1[i-llv] = cosr; w2[i-llv] = sinr;
        }
        Ev(mm-1) = ff;
        if (l < 16){
          for (int j = 0; j < mm-llv; j++){
            float c = w1[j], s = w2[j];
            if (c != 1.f || s != 0.f){
              float tmp = VTm[llv+j][l];
              float t0  = VTm[llv+j-1][l];
              VTm[llv+j][l]   = c*tmp - s*t0;
              VTm[llv+j-1][l] = s*tmp + c*t0;
            }
          }
        }
        if (fabsf(Ev(mm-1)) <= thresh) Ev(mm-1) = 0.f;
      } else {
        float ff = (fabsf(Dv(mm)) - shift)*(copysignf(1.f, Dv(mm)) + shift/Dv(mm));
        float gg = Ev(mm-1);
        float cosr, sinr, cosl, sinl, rr;
        for (int i = mm; i >= llv+1; i--){
          slartg_(ff, gg, cosr, sinr, rr);
          if (i < mm) Ev(i) = rr;
          ff = cosr*Dv(i) + sinr*Ev(i-1);
          Ev(i-1) = cosr*Ev(i-1) - sinr*Dv(i);
          gg = sinr*Dv(i-1);
          Dv(i-1) = cosr*Dv(i-1);
          slartg_(ff, gg, cosl, sinl, rr);
          Dv(i) = rr;
          ff = cosl*Ev(i-1) + sinl*Dv(i-1);
          Dv(i-1) = cosl*Dv(i-1) - sinl*Ev(i-1);
          if (i > llv+1){
            gg = sinl*Ev(i-2);
            Ev(i-2) = cosl*Ev(i-2);
          }
          w3[i-llv-1] = cosr; w4[i-llv-1] = -sinr;
        }
        Ev(llv) = ff;
        if (fabsf(Ev(llv)) <= thresh) Ev(llv) = 0.f;
        if (l < 16){
          for (int j = mm-llv-1; j >= 0; j--){
            float c = w3[j], s = w4[j];
            if (c != 1.f || s != 0.f){
              float tmp = VTm[llv+j][l];
              float t0  = VTm[llv+j-1][l];
              VTm[llv+j][l]   = c*tmp - s*t0;
              VTm[llv+j-1][l] = s*tmp + c*t0;
            }
          }
        }
      }
    }
  }
  // make positive
  for (int i = 1; i <= n; i++){
    if (Dv(i) < 0.f){
      Dv(i) = -Dv(i);
      if (l < 16) VTm[i-1][l] = -VTm[i-1][l];
    }
  }
  // sort decreasing (one transposition per value)
  for (int i = 1; i <= n-1; i++){
    int isub = 1; float smn = Dv(1);
    for (int j = 2; j <= n+1-i; j++){
      if (Dv(j) <= smn){ isub = j; smn = Dv(j); }
    }
    if (isub != n+1-i){
      Dv(isub) = Dv(n+1-i);
      Dv(n+1-i) = smn;
      if (l < 16){
        float tmp = VTm[isub-1][l];
        VTm[isub-1][l] = VTm[n-i][l];
        VTm[n-i][l] = tmp;
      }
    }
  }
  __syncthreads();
  // ormbr('P','R','T'): VT := VT * G(n-1)...G(1)
  for (int i = n-2; i >= 0; i--){
    float tp = taup[i];
    if (tp != 0.f && l < 16){
      int r = l;
      float w = VTm[r][i+1];
      for (int c = i+2; c < n; c++) w += VTm[r][c]*A[i][c];
      w *= tp;
      VTm[r][i+1] -= w;
      for (int c = i+2; c < n; c++) VTm[r][c] -= w*A[i][c];
    }
    __syncthreads();
  }
  for (int idx = l; idx < 256; idx += 64) vtlOut[idx] = VTm[idx>>4][idx&15];
}
#undef Dv
#undef Ev

// K12: R = Qqr * VT_L^T ; Rinv = R^T — written straight to d_out
__global__ __launch_bounds__(256) void k_rout(float* __restrict__ ws, float* __restrict__ out){
  int ty = blockIdx.y;
  const float* Qq = ws + OFF_QQR + (size_t)ty*65536;
  const float* vtl = ws + OFF_VTL + ty*256;
  long long Roff  = ty ? OUT_R2  : OUT_R1;
  long long RIoff = ty ? OUT_RI2 : OUT_RI1;
  __shared__ float V[16][16];
  int t = threadIdx.x;
  V[t>>4][t&15] = vtl[t];
  __syncthreads();
  int row = blockIdx.x*256 + t;
  float mv[16];
  #pragma unroll
  for (int q = 0; q < 4; q++){
    float4 v = ((const float4*)(Qq + (size_t)row*16))[q];
    mv[q*4] = v.x; mv[q*4+1] = v.y; mv[q*4+2] = v.z; mv[q*4+3] = v.w;
  }
  #pragma unroll
  for (int j = 0; j < 16; j++){
    float s = 0.f;
    #pragma unroll
    for (int i = 0; i < 16; i++) s = fmaf(mv[i], V[j][i], s);
    out[Roff + (long long)row*16 + j] = s;
    out[RIoff + (long long)j*4096 + row] = s;
  }
}

// ===========================================================================
extern "C" void kernel_launch(void* const* d_in, const int* in_sizes, int n_in,
                              void* d_out, int out_size, void* d_ws, size_t ws_size,
                              hipStream_t stream){
  const float* x1 = (const float*)d_in[0];
  const float* x2 = (const float*)d_in[1];
  float* out = (float*)d_out;
  float* ws = (float*)d_ws;
  (void)in_sizes; (void)n_in; (void)out_size; (void)ws_size;

  hipMemsetAsync(d_ws, 0, ZERO_FLOATS*sizeof(float), stream);

  // quantiles + hadamard
  k_hadamard_hist<<<dim3(1024), 256, 0, stream>>>(x1, x2, out, ws);
  k_coarse_scan<<<dim3(2), 256, 0, stream>>>(ws);
  k_fine_hist<<<dim3(1024, 2), 256, 0, stream>>>(x1, x2, ws);
  k_fine_scan<<<dim3(2), 1024, 0, stream>>>(ws, out);

  // keys: foldlike split of key(42) = (0,42): child i = threefry(key, (0,i))
  uint32_t a0, a1, b0, b1;
  h_threefry(0u, 42u, 0u, 0u, a0, a1);
  h_threefry(0u, 42u, 0u, 1u, b0, b1);
  k_omega<<<dim3(256, 2), 256, 0, stream>>>(a0, a1, b0, b1, ws);

  // ---- randomized subspace iteration, both tensors in parallel (gridDim.y=2)
  // QR1: Y0 = res*Omega -> Q0
  k_atype<<<dim3(512, 2), 256, 0, stream>>>(x1, x2, ws, OFF_OMT, 0);
  k_tiny<<<dim3(2), 64, 0, stream>>>(ws, OFF_BIGY, 131072, 0);
  k_applyq<<<dim3(32, 2), 256, 0, stream>>>(ws, OFF_BIGY, 131072, OFF_BIGQ, 131072, 8192, 1, 0);
  // QR2: T1 = res^T*Q0 -> Z1 (as Z1^T)
  k_btype<<<dim3(256, 2), 256, 0, stream>>>(x1, x2, ws, 0);
  k_gram<<<dim3(32, 2), 256, 0, stream>>>(ws, 0, 1);
  k_tiny<<<dim3(2), 64, 0, stream>>>(ws, OFF_TBUF + 0*65536, 3*65536, 1);
  k_applyq<<<dim3(16, 2), 256, 0, stream>>>(ws, OFF_TBUF + 0*65536, 3*65536, OFF_ZT, 65536, 4096, 0, 1);
  // QR3: Y1 = res*Z1 -> Q1
  k_atype<<<dim3(512, 2), 256, 0, stream>>>(x1, x2, ws, OFF_ZT, 2);
  k_tiny<<<dim3(2), 64, 0, stream>>>(ws, OFF_BIGY, 131072, 2);
  k_applyq<<<dim3(32, 2), 256, 0, stream>>>(ws, OFF_BIGY, 131072, OFF_BIGQ, 131072, 8192, 1, 0);
  // QR4: T2 = res^T*Q1 -> Z2 (as Z2^T)
  k_btype<<<dim3(256, 2), 256, 0, stream>>>(x1, x2, ws, 1);
  k_gram<<<dim3(32, 2), 256, 0, stream>>>(ws, 1, 3);
  k_tiny<<<dim3(2), 64, 0, stream>>>(ws, OFF_TBUF + 1*65536, 3*65536, 3);
  k_applyq<<<dim3(16, 2), 256, 0, stream>>>(ws, OFF_TBUF + 1*65536, 3*65536, OFF_ZT, 65536, 4096, 0, 1);
  // QR5: Y2 = res*Z2 -> Q2
  k_atype<<<dim3(512, 2), 256, 0, stream>>>(x1, x2, ws, OFF_ZT, 4);
  k_tiny<<<dim3(2), 64, 0, stream>>>(ws, OFF_BIGY, 131072, 4);
  k_applyq<<<dim3(32, 2), 256, 0, stream>>>(ws, OFF_BIGY, 131072, OFF_BIGQ, 131072, 8192, 1, 0);
  // QR6: Bt = res^T*Q2 ; geqrf(Bt) == gelqf(B) -> Qqr, Rg
  k_btype<<<dim3(256, 2), 256, 0, stream>>>(x1, x2, ws, 2);
  k_gram<<<dim3(32, 2), 256, 0, stream>>>(ws, 2, 5);
  k_tiny<<<dim3(2), 64, 0, stream>>>(ws, OFF_TBUF + 2*65536, 3*65536, 5);
  k_applyq<<<dim3(16, 2), 256, 0, stream>>>(ws, OFF_TBUF + 2*65536, 3*65536, OFF_QQR, 65536, 4096, 1, 0);

  // 16x16 gesdd tail + final output GEMM
  k_chain<<<dim3(2), 64, 0, stream>>>(ws);
  k_rout<<<dim3(16, 2), 256, 0, stream>>>(ws, out);
}

// Round 2
// 1707.297 us; speedup vs baseline: 1.8550x; 1.8550x over previous
//
#include <hip/hip_runtime.h>
#include <cstdint>
#include <cstddef>

// ============================================================================
// EfficientMemoryHadamard — round 2: atomic-free restructure.
// Verified assumption stack (round 1 PASSED, absmax 0.124 / thr 0.307):
//  A1: jax threefry_partitionable (foldlike split, bits=o0^o1, ctr=(0,i))
//  A2: quantile = exact order statistic 33218888 (frac==0) -> radix select
//  A3: CPU gesdd tail: gelqf -> gebd2 -> bdsqr -> ormbr -> gemm
//  A4: LAPACK >= 3.10 slartg signs
// ============================================================================

#define DEV __device__ __forceinline__

constexpr long long NTOT = 33554432LL;           // 4*2048*4096
constexpr unsigned long long KSEL = 33218888ULL; // 0-indexed order statistic

constexpr long long OUT_T1  = 33554432LL;
constexpr long long OUT_R1  = 33554433LL;
constexpr long long OUT_RI1 = 33619969LL;
constexpr long long OUT_T2  = 33685505LL;
constexpr long long OUT_R2  = 33685506LL;
constexpr long long OUT_RI2 = 33751042LL;

// ---- workspace layout (float units) ----
// BPART aliases FINE (quantile phase is over before btype runs).
constexpr size_t OFF_FINE   = 0;          // 2 * 1048576 u32 (zeroed, atomics)
constexpr size_t OFF_BPART  = 0;          // 2 * 16 * 65536 (aliases FINE)
constexpr size_t OFF_CHIST  = 2097152;    // 512 * 2 * 2048 u32 partial hists
constexpr size_t OFF_COARSE = 4194304;    // 2 * 2048 u32 final coarse hist
constexpr size_t OFF_SEGS   = 4198400;    // 2 * 1024 u32 fine segment sums
constexpr size_t OFF_SELR   = 4200448;    // 2*4 ints
constexpr size_t OFF_TSEL   = 4200464;    // 2 floats (+pad)
constexpr size_t OFF_OMT    = 4200480;    // 2*65536  omega^T (16x4096)
constexpr size_t OFF_BIGY   = 4331552;    // 2*131072 (8192x16)
constexpr size_t OFF_BIGQ   = 4593696;    // 2*131072 (8192x16)
constexpr size_t OFF_ZT     = 4855840;    // 2*65536  Z^T (16x4096)
constexpr size_t OFF_QQR    = 4986912;    // 2*65536  Qqr (4096x16)
constexpr size_t OFF_TMAT   = 5117984;    // 2*65536  T (4096x16)
constexpr size_t OFF_GRAMP  = 5249056;    // 2*64*256 gram partials
constexpr size_t OFF_S      = 5281824;    // 2*256
constexpr size_t OFF_QTOP   = 5282336;    // 2*256
constexpr size_t OFF_RG     = 5282848;    // 2*256
constexpr size_t OFF_VTL    = 5283360;    // 2*256
// total 5283872 floats ~= 21.1 MB

// ---------------------------------------------------------------------------
#define TFR(a,b,r) { a += b; b = (b << r) | (b >> (32 - r)); b ^= a; }

DEV void d_threefry(uint32_t k0, uint32_t k1, uint32_t x0, uint32_t x1,
                    uint32_t& o0, uint32_t& o1){
  uint32_t ks2 = k0 ^ k1 ^ 0x1BD11BDAu;
  x0 += k0; x1 += k1;
  TFR(x0,x1,13) TFR(x0,x1,15) TFR(x0,x1,26) TFR(x0,x1,6)
  x0 += k1; x1 += ks2 + 1u;
  TFR(x0,x1,17) TFR(x0,x1,29) TFR(x0,x1,16) TFR(x0,x1,24)
  x0 += ks2; x1 += k0 + 2u;
  TFR(x0,x1,13) TFR(x0,x1,15) TFR(x0,x1,26) TFR(x0,x1,6)
  x0 += k0; x1 += k1 + 3u;
  TFR(x0,x1,17) TFR(x0,x1,29) TFR(x0,x1,16) TFR(x0,x1,24)
  x0 += k1; x1 += ks2 + 4u;
  TFR(x0,x1,13) TFR(x0,x1,15) TFR(x0,x1,26) TFR(x0,x1,6)
  x0 += ks2; x1 += k0 + 5u;
  o0 = x0; o1 = x1;
}

static void h_threefry(uint32_t k0, uint32_t k1, uint32_t x0, uint32_t x1,
                       uint32_t& o0, uint32_t& o1){
  uint32_t ks2 = k0 ^ k1 ^ 0x1BD11BDAu;
  x0 += k0; x1 += k1;
  TFR(x0,x1,13) TFR(x0,x1,15) TFR(x0,x1,26) TFR(x0,x1,6)
  x0 += k1; x1 += ks2 + 1u;
  TFR(x0,x1,17) TFR(x0,x1,29) TFR(x0,x1,16) TFR(x0,x1,24)
  x0 += ks2; x1 += k0 + 2u;
  TFR(x0,x1,13) TFR(x0,x1,15) TFR(x0,x1,26) TFR(x0,x1,6)
  x0 += k0; x1 += k1 + 3u;
  TFR(x0,x1,17) TFR(x0,x1,29) TFR(x0,x1,16) TFR(x0,x1,24)
  x0 += k1; x1 += ks2 + 4u;
  TFR(x0,x1,13) TFR(x0,x1,15) TFR(x0,x1,26) TFR(x0,x1,6)
  x0 += ks2; x1 += k0 + 5u;
  o0 = x0; o1 = x1;
}

DEV float erfinv_f32(float x){
  float w = -log1pf(-x*x);
  float p;
  if (w < 5.0f){
    w -= 2.5f;
    p = 2.81022636e-08f;
    p = fmaf(p, w, 3.43273939e-07f);
    p = fmaf(p, w, -3.5233877e-06f);
    p = fmaf(p, w, -4.39150654e-06f);
    p = fmaf(p, w, 0.00021858087f);
    p = fmaf(p, w, -0.00125372503f);
    p = fmaf(p, w, -0.00417768164f);
    p = fmaf(p, w, 0.246640727f);
    p = fmaf(p, w, 1.50140941f);
  } else {
    w = sqrtf(w) - 3.0f;
    p = -0.000200214257f;
    p = fmaf(p, w, 0.000100950558f);
    p = fmaf(p, w, 0.00134934322f);
    p = fmaf(p, w, -0.00367342844f);
    p = fmaf(p, w, 0.00573950773f);
    p = fmaf(p, w, -0.0076224613f);
    p = fmaf(p, w, 0.00943887047f);
    p = fmaf(p, w, 1.00167406f);
    p = fmaf(p, w, 2.83297682f);
  }
  return p * x;
}

DEV float lapy2f(float x, float y){
  float xa = fabsf(x), ya = fabsf(y);
  float w = fmaxf(xa, ya), z = fminf(xa, ya);
  if (z == 0.f) return w;
  float q = z / w;
  return w * sqrtf(1.f + q*q);
}

DEV void slartg_(float f, float g, float& c, float& s, float& r){
  if (g == 0.f){ c = 1.f; s = 0.f; r = f; }
  else if (f == 0.f){ c = 0.f; s = copysignf(1.f, g); r = fabsf(g); }
  else {
    float d = sqrtf(f*f + g*g);
    c = fabsf(f) / d;
    r = copysignf(d, f);
    s = g / r;
  }
}

DEV void slas2_(float f, float g, float h, float& ssmin, float& ssmax){
  float fa = fabsf(f), ga = fabsf(g), ha = fabsf(h);
  float fhmn = fminf(fa, ha), fhmx = fmaxf(fa, ha);
  if (fhmn == 0.f){
    ssmin = 0.f;
    if (fhmx == 0.f) ssmax = ga;
    else {
      float mx = fmaxf(fhmx, ga), mn = fminf(fhmx, ga);
      float q = mn/mx;
      ssmax = mx*sqrtf(1.f + q*q);
    }
  } else {
    if (ga < fhmx){
      float as_ = 1.f + fhmn/fhmx;
      float at_ = (fhmx - fhmn)/fhmx;
      float au = ga/fhmx; au = au*au;
      float cc = 2.f/(sqrtf(as_*as_ + au) + sqrtf(at_*at_ + au));
      ssmin = fhmn*cc; ssmax = fhmx/cc;
    } else {
      float au = fhmx/ga;
      if (au == 0.f){ ssmin = (fhmn*fhmx)/ga; ssmax = ga; }
      else {
        float as_ = 1.f + fhmn/fhmx;
        float at_ = (fhmx - fhmn)/fhmx;
        float q1 = as_*au, q2 = at_*au;
        float cc = 1.f/(sqrtf(1.f + q1*q1) + sqrtf(1.f + q2*q2));
        ssmin = (fhmn*cc)*au; ssmin = ssmin + ssmin;
        ssmax = ga/(cc + cc);
      }
    }
  }
}

DEV void slasv2_(float f, float g, float h, float& ssmin, float& ssmax,
                 float& snr, float& csr, float& snl, float& csl){
  const float eps = 5.9604645e-08f;
  float ft = f, fa = fabsf(f), ht = h, ha = fabsf(h);
  int pmax = 1;
  bool swp = (ha > fa);
  if (swp){ pmax = 3; float t; t=ft; ft=ht; ht=t; t=fa; fa=ha; ha=t; }
  float gt = g, ga = fabsf(g);
  float clt = 0.f, crt = 0.f, slt = 0.f, srt = 0.f;
  if (ga == 0.f){ ssmin = ha; ssmax = fa; clt = 1.f; crt = 1.f; slt = 0.f; srt = 0.f; }
  else {
    bool gasmal = true;
    if (ga > fa){
      pmax = 2;
      if ((fa/ga) < eps){
        gasmal = false;
        ssmax = ga;
        if (ha > 1.f) ssmin = fa/(ga/ha); else ssmin = (fa/ga)*ha;
        clt = 1.f; slt = ht/gt; srt = 1.f; crt = ft/gt;
      }
    }
    if (gasmal){
      float dd = fa - ha;
      float L = (dd == fa) ? 1.f : dd/fa;
      float Mv = gt/ft;
      float T = 2.f - L;
      float MM = Mv*Mv, TT = T*T;
      float Sv = sqrtf(TT + MM);
      float Rv = (L == 0.f) ? fabsf(Mv) : sqrtf(L*L + MM);
      float Av = 0.5f*(Sv + Rv);
      ssmin = ha/Av; ssmax = fa*Av;
      float Tv;
      if (MM == 0.f){
        if (L == 0.f) Tv = copysignf(2.f, ft)*copysignf(1.f, gt);
        else Tv = gt/copysignf(dd, ft) + Mv/T;
      } else {
        Tv = (Mv/(Sv + T) + Mv/(Rv + L))*(1.f + Av);
      }
      float Lv = sqrtf(Tv*Tv + 4.f);
      crt = 2.f/Lv; srt = Tv/Lv;
      clt = (crt + srt*Mv)/Av;
      slt = (ht/ft)*srt/Av;
    }
  }
  if (swp){ csl = srt; snl = crt; csr = slt; snr = clt; }
  else    { csl = clt; snl = slt; csr = crt; snr = srt; }
  float tsign = 1.f;
  if (pmax == 1) tsign = copysignf(1.f, csr)*copysignf(1.f, csl)*copysignf(1.f, f);
  if (pmax == 2) tsign = copysignf(1.f, snr)*copysignf(1.f, csl)*copysignf(1.f, g);
  if (pmax == 3) tsign = copysignf(1.f, snr)*copysignf(1.f, snl)*copysignf(1.f, h);
  ssmax = copysignf(ssmax, tsign);
  ssmin = copysignf(ssmin, tsign*copysignf(1.f, f)*copysignf(1.f, h));
}

// ===========================================================================
// K1: out = x1*x2 fused with 4-way-replicated LDS coarse hists; per-block
//     partials to scratch (NO global atomics).
// ===========================================================================
__global__ __launch_bounds__(256) void k_hadamard_hist(const float* __restrict__ x1,
    const float* __restrict__ x2, float* __restrict__ out, float* __restrict__ ws){
  __shared__ uint32_t lh[2][4][2048];   // 64 KB -> 2 blocks/CU
  for (int i = threadIdx.x; i < 2*4*2048; i += 256) (&lh[0][0][0])[i] = 0u;
  __syncthreads();
  int rep = threadIdx.x & 3;
  const float4* a4 = (const float4*)x1;
  const float4* b4 = (const float4*)x2;
  float4* o4 = (float4*)out;
  long long n4 = NTOT/4;
  long long stride = (long long)gridDim.x * 256;
  for (long long i = (long long)blockIdx.x*256 + threadIdx.x; i < n4; i += stride){
    float4 a = a4[i], b = b4[i];
    float4 o; o.x=a.x*b.x; o.y=a.y*b.y; o.z=a.z*b.z; o.w=a.w*b.w;
    o4[i] = o;
    atomicAdd(&lh[0][rep][(__float_as_uint(a.x)&0x7fffffffu)>>20], 1u);
    atomicAdd(&lh[0][rep][(__float_as_uint(a.y)&0x7fffffffu)>>20], 1u);
    atomicAdd(&lh[0][rep][(__float_as_uint(a.z)&0x7fffffffu)>>20], 1u);
    atomicAdd(&lh[0][rep][(__float_as_uint(a.w)&0x7fffffffu)>>20], 1u);
    atomicAdd(&lh[1][rep][(__float_as_uint(b.x)&0x7fffffffu)>>20], 1u);
    atomicAdd(&lh[1][rep][(__float_as_uint(b.y)&0x7fffffffu)>>20], 1u);
    atomicAdd(&lh[1][rep][(__float_as_uint(b.z)&0x7fffffffu)>>20], 1u);
    atomicAdd(&lh[1][rep][(__float_as_uint(b.w)&0x7fffffffu)>>20], 1u);
  }
  __syncthreads();
  uint32_t* ch = (uint32_t*)(ws + OFF_CHIST);
  for (int i = threadIdx.x; i < 2048; i += 256){
    uint32_t c0 = lh[0][0][i] + lh[0][1][i] + lh[0][2][i] + lh[0][3][i];
    uint32_t c1 = lh[1][0][i] + lh[1][1][i] + lh[1][2][i] + lh[1][3][i];
    ch[((size_t)blockIdx.x*2 + 0)*2048 + i] = c0;
    ch[((size_t)blockIdx.x*2 + 1)*2048 + i] = c1;
  }
}

// K1b: reduce 512 partial coarse hists -> final 2048-bin hist per tensor
__global__ __launch_bounds__(256) void k_coarse_red(float* __restrict__ ws){
  int ty = blockIdx.y;
  const uint32_t* ch = (const uint32_t*)(ws + OFF_CHIST);
  uint32_t* h = (uint32_t*)(ws + OFF_COARSE) + ty*2048;
  int bin = blockIdx.x*128 + (threadIdx.x & 127);
  int half = threadIdx.x >> 7;
  uint32_t s = 0;
  for (int p = half*256; p < half*256 + 256; p++)
    s += ch[((size_t)p*2 + ty)*2048 + bin];
  __shared__ uint32_t sh[256];
  sh[threadIdx.x] = s;
  __syncthreads();
  if (threadIdx.x < 128) h[bin] = sh[threadIdx.x] + sh[threadIdx.x + 128];
}

// K2: scan coarse histogram -> (coarse bin, rank within bin)
__global__ __launch_bounds__(256) void k_coarse_scan(float* __restrict__ ws){
  int ty = blockIdx.x;
  const uint32_t* h = (const uint32_t*)(ws + OFF_COARSE) + ty*2048;
  int* selr = (int*)(ws + OFF_SELR) + ty*4;
  __shared__ unsigned long long ps[256];
  unsigned long long s = 0;
  for (int j = 0; j < 8; j++) s += h[threadIdx.x*8 + j];
  ps[threadIdx.x] = s;
  __syncthreads();
  if (threadIdx.x == 0){
    unsigned long long cum = 0, K = KSEL;
    int g = 0;
    for (; g < 256; g++){ if (cum + ps[g] > K) break; cum += ps[g]; }
    if (g > 255) g = 255;
    int bin = 2047;
    for (int j = 0; j < 8; j++){
      uint32_t c = h[g*8 + j];
      if (cum + c > K){ bin = g*8 + j; break; }
      cum += c;
    }
    selr[0] = bin;
    selr[1] = (int)(K - cum);
  }
}

// K3: fine 20-bit histogram inside the selected coarse bin (sparse atomics OK)
__global__ __launch_bounds__(256) void k_fine_hist(const float* __restrict__ x1,
    const float* __restrict__ x2, float* __restrict__ ws){
  int ty = blockIdx.y;
  const float4* x4 = (const float4*)(ty ? x2 : x1);
  const int* selr = (const int*)(ws + OFF_SELR) + ty*4;
  uint32_t bin = (uint32_t)selr[0];
  uint32_t* f = (uint32_t*)(ws + OFF_FINE) + (size_t)ty*1048576;
  long long n4 = NTOT/4;
  long long stride = (long long)gridDim.x * 256;
  for (long long i = (long long)blockIdx.x*256 + threadIdx.x; i < n4; i += stride){
    float4 a = x4[i];
    uint32_t u;
    u = __float_as_uint(a.x)&0x7fffffffu; if ((u>>20)==bin) atomicAdd(&f[u&0xFFFFFu],1u);
    u = __float_as_uint(a.y)&0x7fffffffu; if ((u>>20)==bin) atomicAdd(&f[u&0xFFFFFu],1u);
    u = __float_as_uint(a.z)&0x7fffffffu; if ((u>>20)==bin) atomicAdd(&f[u&0xFFFFFu],1u);
    u = __float_as_uint(a.w)&0x7fffffffu; if ((u>>20)==bin) atomicAdd(&f[u&0xFFFFFu],1u);
  }
}

// K4a: coalesced per-1024-bin segment sums of the fine histogram
__global__ __launch_bounds__(256) void k_seg_sum(float* __restrict__ ws){
  int ty = blockIdx.y;
  const uint32_t* f = (const uint32_t*)(ws + OFF_FINE) + ((size_t)ty<<20);
  uint32_t* segs = (uint32_t*)(ws + OFF_SEGS) + ty*1024;
  uint32_t s = 0;
  int base = blockIdx.x*1024;
  for (int k = 0; k < 4; k++) s += f[base + k*256 + threadIdx.x];
  __shared__ uint32_t sh[256];
  sh[threadIdx.x] = s;
  __syncthreads();
  for (int off = 128; off > 0; off >>= 1){
    if (threadIdx.x < off) sh[threadIdx.x] += sh[threadIdx.x + off];
    __syncthreads();
  }
  if (threadIdx.x == 0) segs[blockIdx.x] = sh[0];
}

// K4b: find exact order-statistic bit pattern = threshold t
__global__ __launch_bounds__(256) void k_fine_scan2(float* __restrict__ ws, float* __restrict__ out){
  int ty = blockIdx.x;
  const uint32_t* f = (const uint32_t*)(ws + OFF_FINE) + ((size_t)ty<<20);
  const uint32_t* segs = (const uint32_t*)(ws + OFF_SEGS) + ty*1024;
  const int* selr = (const int*)(ws + OFF_SELR) + ty*4;
  __shared__ uint32_t sh[1024];
  __shared__ uint32_t ps[256];
  __shared__ int gsel; __shared__ uint32_t csel;
  int t = threadIdx.x;
  uint32_t K = (uint32_t)selr[1];
  // ---- pass 1: pick 1024-bin segment
  for (int k = 0; k < 4; k++) sh[k*256 + t] = segs[k*256 + t];
  __syncthreads();
  ps[t] = sh[4*t] + sh[4*t+1] + sh[4*t+2] + sh[4*t+3];
  __syncthreads();
  if (t == 0){
    uint32_t cum = 0; int q = 0;
    for (; q < 256; q++){ if (cum + ps[q] > K) break; cum += ps[q]; }
    if (q > 255) q = 255;
    int g = q*4;
    for (int j = 0; j < 4; j++){
      uint32_t c = sh[q*4 + j];
      if (cum + c > K){ g = q*4 + j; break; }
      cum += c;
      if (j == 3) g = q*4 + 3;
    }
    gsel = g; csel = cum;
  }
  __syncthreads();
  int g = gsel;
  // ---- pass 2: pick bin within segment
  for (int k = 0; k < 4; k++) sh[k*256 + t] = f[(size_t)g*1024 + k*256 + t];
  __syncthreads();
  ps[t] = sh[4*t] + sh[4*t+1] + sh[4*t+2] + sh[4*t+3];
  __syncthreads();
  if (t == 0){
    uint32_t cum = csel; int q = 0;
    for (; q < 256; q++){ if (cum + ps[q] > K) break; cum += ps[q]; }
    if (q > 255) q = 255;
    int j = q*4 + 3;
    for (int jj = 0; jj < 4; jj++){
      uint32_t c = sh[q*4 + jj];
      if (cum + c > K){ j = q*4 + jj; break; }
      cum += c;
    }
    uint32_t bits = (((uint32_t)selr[0])<<20) | (uint32_t)((g*1024 + j) & 0xFFFFF);
    float th = __uint_as_float(bits);
    ws[OFF_TSEL + ty] = th;
    out[ty ? OUT_T2 : OUT_T1] = th;
  }
}

// K5: omega^T via threefry
__global__ __launch_bounds__(256) void k_omega(uint32_t a0, uint32_t a1,
    uint32_t b0, uint32_t b1, float* __restrict__ ws){
  int ty = blockIdx.y;
  uint32_t k0 = ty ? b0 : a0, k1 = ty ? b1 : a1;
  int i = blockIdx.x*256 + threadIdx.x;
  uint32_t o0, o1;
  d_threefry(k0, k1, 0u, (uint32_t)i, o0, o1);
  uint32_t bits = o0 ^ o1;
  float fr = __uint_as_float((bits >> 9) | 0x3f800000u) - 1.0f;
  const float lo = -0.99999994f;
  float u = fr * 2.0f + lo;
  u = fmaxf(lo, u);
  float v = 1.41421356237f * erfinv_f32(u);
  int row = i >> 4, col = i & 15;
  ws[OFF_OMT + (size_t)ty*65536 + (size_t)col*4096 + row] = v;
}

// K6: A-type matmul  Y(8192x16) = residual(x) * W   (W given as W^T 16x4096)
//     W-tile float4s hoisted out of the row loop (x in regs) -> 4x fewer LDS.
__global__ __launch_bounds__(256) void k_atype(const float* __restrict__ x1,
    const float* __restrict__ x2, float* __restrict__ ws, size_t wtOff){
  int ty = blockIdx.y;
  const float* x = ty ? x2 : x1;
  const float* wt = ws + wtOff + (size_t)ty*65536;
  float* Y = ws + OFF_BIGY + (size_t)ty*131072;
  float t = ws[OFF_TSEL + ty];
  int wave = threadIdx.x >> 6, lane = threadIdx.x & 63;
  __shared__ __align__(16) float wts[16][256];
  __shared__ float outs[16][16];
  float acc[4][16];
  #pragma unroll
  for (int r = 0; r < 4; r++)
    #pragma unroll
    for (int j = 0; j < 16; j++) acc[r][j] = 0.f;
  int rowbase = blockIdx.x*16 + wave*4;
  for (int c = 0; c < 4096; c += 256){
    __syncthreads();
    for (int idx = threadIdx.x; idx < 16*64; idx += 256){
      int j = idx >> 6, q = idx & 63;
      ((float4*)&wts[j][0])[q] = ((const float4*)(wt + (size_t)j*4096 + c))[q];
    }
    __syncthreads();
    float4 xv[4];
    #pragma unroll
    for (int rr = 0; rr < 4; rr++){
      int row = rowbase + rr;
      float4 a = ((const float4*)(x + (size_t)row*4096 + c))[lane];
      a.x = fabsf(a.x) > t ? 0.f : a.x;
      a.y = fabsf(a.y) > t ? 0.f : a.y;
      a.z = fabsf(a.z) > t ? 0.f : a.z;
      a.w = fabsf(a.w) > t ? 0.f : a.w;
      xv[rr] = a;
    }
    #pragma unroll
    for (int j = 0; j < 16; j++){
      float4 w4 = ((const float4*)&wts[j][0])[lane];
      #pragma unroll
      for (int rr = 0; rr < 4; rr++){
        acc[rr][j] = fmaf(xv[rr].x, w4.x, acc[rr][j]);
        acc[rr][j] = fmaf(xv[rr].y, w4.y, acc[rr][j]);
        acc[rr][j] = fmaf(xv[rr].z, w4.z, acc[rr][j]);
        acc[rr][j] = fmaf(xv[rr].w, w4.w, acc[rr][j]);
      }
    }
  }
  #pragma unroll
  for (int rr = 0; rr < 4; rr++)
    for (int j = 0; j < 16; j++){
      float v = acc[rr][j];
      for (int off = 32; off > 0; off >>= 1) v += __shfl_xor(v, off, 64);
      if (lane == 0) outs[wave*4 + rr][j] = v;
    }
  __syncthreads();
  int r = threadIdx.x >> 4, cc = threadIdx.x & 15;
  Y[(size_t)(blockIdx.x*16 + r)*16 + cc] = outs[r][cc];
}

// K6b: partial gram of M (rows x 16), 128 rows/chunk, skip top-16 rows of chunk 0
__global__ __launch_bounds__(256) void k_gramP(float* __restrict__ ws, size_t mOff,
    size_t mStr){
  int ty = blockIdx.y;
  const float* M = ws + mOff + (size_t)ty*mStr;
  float* gp = ws + OFF_GRAMP + (size_t)(ty*64 + blockIdx.x)*256;
  __shared__ __align__(16) float buf[128][16];
  int t = threadIdx.x;
  for (int q = t; q < 512; q += 256)
    ((float4*)&buf[0][0])[q] = ((const float4*)(M + (size_t)blockIdx.x*2048))[q];
  __syncthreads();
  int i = t >> 4, j = t & 15;
  float s = 0.f;
  int rstart = (blockIdx.x == 0) ? 16 : 0;
  for (int r = rstart; r < 128; r++) s += buf[r][i]*buf[r][j];
  gp[t] = s;
}

// K7: B-type matmul partials: BP[rc] = residual(x[rows rc])^T * Q  (no atomics)
__global__ __launch_bounds__(256) void k_btype(const float* __restrict__ x1,
    const float* __restrict__ x2, float* __restrict__ ws){
  int ty = blockIdx.y;
  const float* x = ty ? x2 : x1;
  const float* Q = ws + OFF_BIGQ + (size_t)ty*131072;
  float t = ws[OFF_TSEL + ty];
  int cb = blockIdx.x & 15;    // column block (256 cols)
  int rc = blockIdx.x >> 4;    // row chunk (512 rows)
  int c = cb*256 + threadIdx.x;
  int r0 = rc*512;
  __shared__ __align__(16) float Qs[64][16];
  float acc[16];
  #pragma unroll
  for (int j = 0; j < 16; j++) acc[j] = 0.f;
  for (int tile = 0; tile < 8; tile++){
    __syncthreads();
    ((float4*)&Qs[0][0])[threadIdx.x] =
        ((const float4*)(Q + (size_t)(r0 + tile*64)*16))[threadIdx.x];
    __syncthreads();
    const float* xp = x + (size_t)(r0 + tile*64)*4096 + c;
    #pragma unroll 4
    for (int rr = 0; rr < 64; rr++){
      float v = xp[(size_t)rr*4096];
      v = fabsf(v) > t ? 0.f : v;
      float4 qa = ((const float4*)&Qs[rr][0])[0];   // wave-uniform broadcast
      float4 qb = ((const float4*)&Qs[rr][0])[1];
      float4 qc = ((const float4*)&Qs[rr][0])[2];
      float4 qd = ((const float4*)&Qs[rr][0])[3];
      acc[ 0] = fmaf(v, qa.x, acc[ 0]);
      acc[ 1] = fmaf(v, qa.y, acc[ 1]);
      acc[ 2] = fmaf(v, qa.z, acc[ 2]);
      acc[ 3] = fmaf(v, qa.w, acc[ 3]);
      acc[ 4] = fmaf(v, qb.x, acc[ 4]);
      acc[ 5] = fmaf(v, qb.y, acc[ 5]);
      acc[ 6] = fmaf(v, qb.z, acc[ 6]);
      acc[ 7] = fmaf(v, qb.w, acc[ 7]);
      acc[ 8] = fmaf(v, qc.x, acc[ 8]);
      acc[ 9] = fmaf(v, qc.y, acc[ 9]);
      acc[10] = fmaf(v, qc.z, acc[10]);
      acc[11] = fmaf(v, qc.w, acc[11]);
      acc[12] = fmaf(v, qd.x, acc[12]);
      acc[13] = fmaf(v, qd.y, acc[13]);
      acc[14] = fmaf(v, qd.z, acc[14]);
      acc[15] = fmaf(v, qd.w, acc[15]);
    }
  }
  float* BP = ws + OFF_BPART + (((size_t)(ty*16 + rc))<<16) + (size_t)c*16;
  #pragma unroll
  for (int q = 0; q < 4; q++){
    float4 o; o.x = acc[q*4]; o.y = acc[q*4+1]; o.z = acc[q*4+2]; o.w = acc[q*4+3];
    ((float4*)BP)[q] = o;
  }
}

// K7b: reduce 16 BP partials -> T, fused with partial gram of T (64-col tiles)
__global__ __launch_bounds__(256) void k_bredgram(float* __restrict__ ws){
  int ty = blockIdx.y;
  const float* BP = ws + OFF_BPART + (((size_t)ty*16)<<16);
  float* T = ws + OFF_TMAT + (size_t)ty*65536;
  float* gp = ws + OFF_GRAMP + (size_t)(ty*64 + blockIdx.x)*256;
  __shared__ float sh[64][16];
  int t = threadIdx.x;
  for (int k = 0; k < 4; k++){
    int e = blockIdx.x*1024 + k*256 + t;
    float s = 0.f;
    #pragma unroll
    for (int rc = 0; rc < 16; rc++) s += BP[((size_t)rc<<16) + e];
    T[e] = s;
    int le = k*256 + t;
    sh[le >> 4][le & 15] = s;
  }
  __syncthreads();
  int i = t >> 4, j = t & 15;
  float s = 0.f;
  int rstart = (blockIdx.x == 0) ? 16 : 0;   // skip top-16 rows of T
  for (int r = rstart; r < 64; r++) s += sh[r][i]*sh[r][j];
  gp[t] = s;
}

// K9: tiny per-QR kernel (sums 64 gram partials; then chol/geqrf/org2r/solve)
__global__ __launch_bounds__(64) void k_tiny(float* __restrict__ ws, size_t mOff,
    size_t mStr){
  int ty = blockIdx.x;
  const float* Mp = ws + mOff + (size_t)ty*mStr;
  float* sOut = ws + OFF_S + ty*256;
  float* qtOut = ws + OFF_QTOP + ty*256;
  float* rgOut = ws + OFF_RG + ty*256;
  __shared__ float G[16][16];
  __shared__ float C[32][16];
  __shared__ float Qs[32][16];
  __shared__ float S[16][16];
  __shared__ float tau[16];
  int l = threadIdx.x;
  for (int e = l; e < 256; e += 64){
    const float* gp = ws + OFF_GRAMP + (size_t)ty*16384 + e;
    float s = 0.f;
    for (int p = 0; p < 64; p++) s += gp[(size_t)p*256];
    G[e>>4][e&15] = s;
  }
  __syncthreads();
  // cholesky (upper) in place
  for (int k = 0; k < 16; k++){
    float dk = sqrtf(G[k][k]);
    if (l == k) G[k][k] = dk;
    else if (l > k && l < 16) G[k][l] = G[k][l] / dk;
    __syncthreads();
    if (l > k && l < 16)
      for (int j = l; j < 16; j++) G[l][j] -= G[k][l]*G[k][j];
    __syncthreads();
  }
  // C = [M_top ; R_B]
  for (int idx = l; idx < 512; idx += 64){
    int r = idx >> 4, c = idx & 15;
    float v;
    if (r < 16) v = Mp[r*16 + c];
    else v = (c >= r - 16) ? G[r-16][c] : 0.f;
    C[r][c] = v;
  }
  __syncthreads();
  // LAPACK-convention geqrf on 32x16 C
  for (int i = 0; i < 16; i++){
    float alpha = C[i][i];
    float ssum = 0.f;
    for (int r = i+1; r < 32; r++) ssum += C[r][i]*C[r][i];
    float xn = sqrtf(ssum);
    float beta, tv;
    if (xn == 0.f){ tv = 0.f; beta = alpha; }
    else {
      beta = -copysignf(lapy2f(alpha, xn), alpha);
      tv = (beta - alpha)/beta;
      float sc = 1.f/(alpha - beta);
      if (l > i && l < 32) C[l][i] *= sc;
    }
    if (l == 0){ C[i][i] = beta; tau[i] = tv; }
    __syncthreads();
    if (tv != 0.f && l > i && l < 16){
      int j = l;
      float w = C[i][j];
      for (int r = i+1; r < 32; r++) w += C[r][i]*C[r][j];
      w *= tv;
      C[i][j] -= w;
      for (int r = i+1; r < 32; r++) C[r][j] -= w*C[r][i];
    }
    __syncthreads();
  }
  for (int idx = l; idx < 256; idx += 64){
    int r = idx >> 4, c = idx & 15;
    rgOut[idx] = (c >= r) ? C[r][c] : 0.f;
  }
  // org2r
  for (int idx = l; idx < 512; idx += 64) Qs[idx>>4][idx&15] = 0.f;
  __syncthreads();
  for (int i = 15; i >= 0; i--){
    float tv = tau[i];
    if (i < 15 && l > i && l < 16){
      int j = l;
      float w = Qs[i][j];
      for (int r = i+1; r < 32; r++) w += C[r][i]*Qs[r][j];
      w *= tv;
      Qs[i][j] -= w;
      for (int r = i+1; r < 32; r++) Qs[r][j] -= w*C[r][i];
    }
    __syncthreads();
    if (l > i && l < 32) Qs[l][i] = -tv * C[l][i];
    if (l == i) Qs[i][i] = 1.f - tv;
    if (l < i) Qs[l][i] = 0.f;
    __syncthreads();
  }
  // back-solve S = R_B^{-1} * Qs[16:32]
  if (l < 16){
    int j = l;
    for (int i2 = 15; i2 >= 0; i2--){
      float v = Qs[16 + i2][j];
      for (int k2 = i2+1; k2 < 16; k2++) v -= G[i2][k2]*S[k2][j];
      S[i2][j] = v / G[i2][i2];
    }
  }
  __syncthreads();
  for (int idx = l; idx < 256; idx += 64){
    sOut[idx] = S[idx>>4][idx&15];
    qtOut[idx] = Qs[idx>>4][idx&15];
  }
}

// K10: Q = [Q_top ; M(17:,:)*S]  (normal and/or transposed output layout)
__global__ __launch_bounds__(256) void k_applyq(float* __restrict__ ws, size_t mOff,
    size_t mStr, size_t oOff, size_t oStr, int nrows, int wN, int wT){
  int ty = blockIdx.y;
  const float* Mp = ws + mOff + (size_t)ty*mStr;
  const float* sP = ws + OFF_S + ty*256;
  const float* qtP = ws + OFF_QTOP + ty*256;
  float* oP = ws + oOff + (size_t)ty*oStr;
  __shared__ float Ss[16][16], Qt[16][16];
  int t = threadIdx.x;
  Ss[t>>4][t&15] = sP[t];
  Qt[t>>4][t&15] = qtP[t];
  __syncthreads();
  int row = blockIdx.x*256 + t;
  if (row >= nrows) return;
  float o[16];
  if (row < 16){
    #pragma unroll
    for (int j = 0; j < 16; j++) o[j] = Qt[row][j];
  } else {
    float mv[16];
    #pragma unroll
    for (int q = 0; q < 4; q++){
      float4 v = ((const float4*)(Mp + (size_t)row*16))[q];
      mv[q*4] = v.x; mv[q*4+1] = v.y; mv[q*4+2] = v.z; mv[q*4+3] = v.w;
    }
    #pragma unroll
    for (int j = 0; j < 16; j++){
      float sacc = 0.f;
      #pragma unroll
      for (int i = 0; i < 16; i++) sacc = fmaf(mv[i], Ss[i][j], sacc);
      o[j] = sacc;
    }
  }
  if (wN){
    #pragma unroll
    for (int q = 0; q < 4; q++){
      float4 v; v.x = o[q*4]; v.y = o[q*4+1]; v.z = o[q*4+2]; v.w = o[q*4+3];
      ((float4*)(oP + (size_t)row*16))[q] = v;
    }
  }
  if (wT){
    #pragma unroll
    for (int j = 0; j < 16; j++) oP[(size_t)j*4096 + row] = o[j];
  }
}

// K11: 16x16 gesdd tail: gebd2 -> bdsqr (VT only) -> ormbr('P','R','T')
#define Dv(i) d_[(i)-1]
#define Ev(i) e_[(i)-1]
__global__ __launch_bounds__(64) void k_chain(float* __restrict__ ws){
  int ty = blockIdx.x;
  const float* rg = ws + OFF_RG + ty*256;
  float* vtlOut = ws + OFF_VTL + ty*256;
  const int n = 16;
  __shared__ float A[16][16];
  __shared__ float VTm[16][16];
  __shared__ float d_[16], e_[16], tauq[16], taup[16];
  __shared__ float w1[16], w2[16], w3[16], w4[16];
  int l = threadIdx.x;
  for (int idx = l; idx < 256; idx += 64){
    int r = idx >> 4, c = idx & 15;
    A[r][c] = (r >= c) ? rg[c*16 + r] : 0.f;   // L = Rg^T
  }
  __syncthreads();
  // ---- gebd2 ----
  for (int i = 0; i < n; i++){
    {
      float alpha = A[i][i];
      float ssum = 0.f;
      for (int r = i+1; r < n; r++) ssum += A[r][i]*A[r][i];
      float xn = sqrtf(ssum);
      float beta, tv;
      if (n - i <= 1 || xn == 0.f){ tv = 0.f; beta = alpha; }
      else {
        beta = -copysignf(lapy2f(alpha, xn), alpha);
        tv = (beta - alpha)/beta;
        float sc = 1.f/(alpha - beta);
        if (l > i && l < n) A[l][i] *= sc;
      }
      if (l == 0){ d_[i] = beta; tauq[i] = tv; }
      __syncthreads();
      if (tv != 0.f && l > i && l < n){
        int j = l;
        float w = A[i][j];
        for (int r = i+1; r < n; r++) w += A[r][i]*A[r][j];
        w *= tv;
        A[i][j] -= w;
        for (int r = i+1; r < n; r++) A[r][j] -= w*A[r][i];
      }
      __syncthreads();
    }
    if (i < n-1){
      float alpha = A[i][i+1];
      float ssum = 0.f;
      for (int c = i+2; c < n; c++) ssum += A[i][c]*A[i][c];
      float xn = sqrtf(ssum);
      float beta, tp;
      if (n - i - 1 <= 1 || xn == 0.f){ tp = 0.f; beta = alpha; }
      else {
        beta = -copysignf(lapy2f(alpha, xn), alpha);
        tp = (beta - alpha)/beta;
        float sc = 1.f/(alpha - beta);
        if (l >= i+2 && l < n) A[i][l] *= sc;
      }
      if (l == 0){ e_[i] = beta; taup[i] = tp; }
      __syncthreads();
      if (tp != 0.f && l > i && l < n){
        int r = l;
        float w = A[r][i+1];
        for (int c = i+2; c < n; c++) w += A[i][c]*A[r][c];
        w *= tp;
        A[r][i+1] -= w;
        for (int c = i+2; c < n; c++) A[r][c] -= w*A[i][c];
      }
      __syncthreads();
    } else {
      if (l == 0) taup[i] = 0.f;
      __syncthreads();
    }
  }
  for (int idx = l; idx < 256; idx += 64){
    int r = idx >> 4, c = idx & 15;
    VTm[r][c] = (r == c) ? 1.f : 0.f;
  }
  __syncthreads();
  // ---- bdsqr ('U', ncvt=16, nru=0, ncc=0) ----
  const float eps = 5.9604645e-08f;
  const float unfl = 1.17549435e-38f;
  const float tol = 10.f*eps;
  float sminoa = fabsf(Dv(1));
  if (sminoa != 0.f){
    float mu = sminoa;
    for (int i = 2; i <= n; i++){
      mu = fabsf(Dv(i))*(mu/(mu + fabsf(Ev(i-1))));
      sminoa = fminf(sminoa, mu);
      if (sminoa == 0.f) break;
    }
  }
  sminoa = sminoa / sqrtf((float)n);
  float thresh = fmaxf(tol*sminoa, (float)(6*n*n)*unfl);
  int maxit = 6*n*n;
  int iter = 0, oldll = -1, oldm = -1, mm = n, idir = 0;
  while (true){
    if (mm <= 1) break;
    if (iter > maxit) break;
    float smaxw = fabsf(Dv(mm));
    int llv = 0; bool split = false;
    for (int lll = 1; lll <= mm-1; lll++){
      llv = mm - lll;
      float abss = fabsf(Dv(llv));
      float abse = fabsf(Ev(llv));
      if (abse <= thresh){ split = true; break; }
      smaxw = fmaxf(smaxw, fmaxf(abss, abse));
    }
    if (split){
      Ev(llv) = 0.f;
      if (llv == mm-1){ mm = mm - 1; continue; }
      llv = llv + 1;
    } else llv = 1;
    if (llv == mm-1){
      float sigmn, sigmx, sinr, cosr, sinl, cosl;
      slasv2_(Dv(mm-1), Ev(mm-1), Dv(mm), sigmn, sigmx, sinr, cosr, sinl, cosl);
      Dv(mm-1) = sigmx; Ev(mm-1) = 0.f; Dv(mm) = sigmn;
      if (l < 16){
        float tA = VTm[mm-2][l], tB = VTm[mm-1][l];
        VTm[mm-2][l] = cosr*tA + sinr*tB;
        VTm[mm-1][l] = cosr*tB - sinr*tA;
      }
      mm -= 2;
      continue;
    }
    if (llv > oldm || mm < oldll)
      idir = (fabsf(Dv(llv)) >= fabsf(Dv(mm))) ? 1 : 2;
    bool deflated = false;
    float sminl = 0.f;
    if (idir == 1){
      if (fabsf(Ev(mm-1)) <= tol*fabsf(Dv(mm))){ Ev(mm-1) = 0.f; continue; }
      float mu = fabsf(Dv(llv)); sminl = mu;
      for (int lll = llv; lll <= mm-1; lll++){
        if (fabsf(Ev(lll)) <= tol*mu){ Ev(lll) = 0.f; deflated = true; break; }
        mu = fabsf(Dv(lll+1))*(mu/(mu + fabsf(Ev(lll))));
        sminl = fminf(sminl, mu);
      }
    } else {
      if (fabsf(Ev(llv)) <= tol*fabsf(Dv(llv))){ Ev(llv) = 0.f; continue; }
      float mu = fabsf(Dv(mm)); sminl = mu;
      for (int lll = mm-1; lll >= llv; lll--){
        if (fabsf(Ev(lll)) <= tol*mu){ Ev(lll) = 0.f; deflated = true; break; }
        mu = fabsf(Dv(lll))*(mu/(mu + fabsf(Ev(lll))));
        sminl = fminf(sminl, mu);
      }
    }
    if (deflated) continue;
    oldll = llv; oldm = mm;
    float shift = 0.f, rdum;
    if (!((float)n*tol*(sminl/smaxw) <= fmaxf(eps, 0.01f*tol))){
      float sll;
      if (idir == 1){ sll = fabsf(Dv(llv)); slas2_(Dv(mm-1), Ev(mm-1), Dv(mm), shift, rdum); }
      else          { sll = fabsf(Dv(mm));  slas2_(Dv(llv), Ev(llv), Dv(llv+1), shift, rdum); }
      if (sll > 0.f){ float q = shift/sll; if (q*q < eps) shift = 0.f; }
    }
    iter += mm - llv;
    if (shift == 0.f){
      if (idir == 1){
        float cs = 1.f, oldcs = 1.f, sn = 0.f, oldsn = 0.f, rr, dnew;
        for (int i = llv; i <= mm-1; i++){
          slartg_(Dv(i)*cs, Ev(i), cs, sn, rr);
          if (i > llv) Ev(i-1) = oldsn*rr;
          slartg_(oldcs*rr, Dv(i+1)*sn, oldcs, oldsn, dnew);
          Dv(i) = dnew;
          w1[i-llv] = cs; w2[i-llv] = sn;
        }
        float h = Dv(mm)*cs;
        Dv(mm) = h*oldcs;
        Ev(mm-1) = h*oldsn;
        if (l < 16){
          for (int j = 0; j < mm-llv; j++){
            float c = w1[j], s = w2[j];
            if (c != 1.f || s != 0.f){
              float tmp = VTm[llv+j][l];
              float t0  = VTm[llv+j-1][l];
              VTm[llv+j][l]   = c*tmp - s*t0;
              VTm[llv+j-1][l] = s*tmp + c*t0;
            }
          }
        }
        if (fabsf(Ev(mm-1)) <= thresh) Ev(mm-1) = 0.f;
      } else {
        float cs = 1.f, oldcs = 1.f, sn = 0.f, oldsn = 0.f, rr, dnew;
        for (int i = mm; i >= llv+1; i--){
          slartg_(Dv(i)*cs, Ev(i-1), cs, sn, rr);
          if (i < mm) Ev(i) = oldsn*rr;
          slartg_(oldcs*rr, Dv(i-1)*sn, oldcs, oldsn, dnew);
          Dv(i) = dnew;
          w3[i-llv-1] = oldcs; w4[i-llv-1] = -oldsn;
        }
        float h = Dv(llv)*cs;
        Dv(llv) = h*oldcs;
        Ev(llv) = h*oldsn;
        if (l < 16){
          for (int j = mm-llv-1; j >= 0; j--){
            float c = w3[j], s = w4[j];
            if (c != 1.f || s != 0.f){
              float tmp = VTm[llv+j][l];
              float t0  = VTm[llv+j-1][l];
              VTm[llv+j][l]   = c*tmp - s*t0;
              VTm[llv+j-1][l] = s*tmp + c*t0;
            }
          }
        }
        if (fabsf(Ev(llv)) <= thresh) Ev(llv) = 0.f;
      }
    } else {
      if (idir == 1){
        float ff = (fabsf(Dv(llv)) - shift)*(copysignf(1.f, Dv(llv)) + shift/Dv(llv));
        float gg = Ev(llv);
        float cosr, sinr, cosl, sinl, rr;
        for (int i = llv; i <= mm-1; i++){
          slartg_(ff, gg, cosr, sinr, rr);
          if (i > llv) Ev(i-1) = rr;
          ff = cosr*Dv(i) + sinr*Ev(i);
          Ev(i) = cosr*Ev(i) - sinr*Dv(i);
          gg = sinr*Dv(i+1);
          Dv(i+1) = cosr*Dv(i+1);
          slartg_(ff, gg, cosl, sinl, rr);
          Dv(i) = rr;
          ff = cosl*Ev(i) + sinl*Dv(i+1);
          Dv(i+1) = cosl*Dv(i+1) - sinl*Ev(i);
          if (i < mm-1){
            gg = sinl*Ev(i+1);
            Ev(i+1) = cosl*Ev(i+1);
          }
          w1[i-llv] = cosr; w2[i-llv] = sinr;
        }
        Ev(mm-1) = ff;
        if (l < 16){
          for (int j = 0; j < mm-llv; j++){
            float c = w1[j], s = w2[j];
            if (c != 1.f || s != 0.f){
              float tmp = VTm[llv+j][l];
              float t0  = VTm[llv+j-1][l];
              VTm[llv+j][l]   = c*tmp - s*t0;
              VTm[llv+j-1][l] = s*tmp + c*t0;
            }
          }
        }
        if (fabsf(Ev(mm-1)) <= thresh) Ev(mm-1) = 0.f;
      } else {
        float ff = (fabsf(Dv(mm)) - shift)*(copysignf(1.f, Dv(mm)) + shift/Dv(mm));
        float gg = Ev(mm-1);
        float cosr, sinr, cosl, sinl, rr;
        for (int i = mm; i >= llv+1; i--){
          slartg_(ff, gg, cosr, sinr, rr);
          if (i < mm) Ev(i) = rr;
          ff = cosr*Dv(i) + sinr*Ev(i-1);
          Ev(i-1) = cosr*Ev(i-1) - sinr*Dv(i);
          gg = sinr*Dv(i-1);
          Dv(i-1) = cosr*Dv(i-1);
          slartg_(ff, gg, cosl, sinl, rr);
          Dv(i) = rr;
          ff = cosl*Ev(i-1) + sinl*Dv(i-1);
          Dv(i-1) = cosl*Dv(i-1) - sinl*Ev(i-1);
          if (i > llv+1){
            gg = sinl*Ev(i-2);
            Ev(i-2) = cosl*Ev(i-2);
          }
          w3[i-llv-1] = cosr; w4[i-llv-1] = -sinr;
        }
        Ev(llv) = ff;
        if (fabsf(Ev(llv)) <= thresh) Ev(llv) = 0.f;
        if (l < 16){
          for (int j = mm-llv-1; j >= 0; j--){
            float c = w3[j], s = w4[j];
            if (c != 1.f || s != 0.f){
              float tmp = VTm[llv+j][l];
              float t0  = VTm[llv+j-1][l];
              VTm[llv+j][l]   = c*tmp - s*t0;
              VTm[llv+j-1][l] = s*tmp + c*t0;
            }
          }
        }
      }
    }
  }
  // make positive
  for (int i = 1; i <= n; i++){
    if (Dv(i) < 0.f){
      Dv(i) = -Dv(i);
      if (l < 16) VTm[i-1][l] = -VTm[i-1][l];
    }
  }
  // sort decreasing
  for (int i = 1; i <= n-1; i++){
    int isub = 1; float smn = Dv(1);
    for (int j = 2; j <= n+1-i; j++){
      if (Dv(j) <= smn){ isub = j; smn = Dv(j); }
    }
    if (isub != n+1-i){
      Dv(isub) = Dv(n+1-i);
      Dv(n+1-i) = smn;
      if (l < 16){
        float tmp = VTm[isub-1][l];
        VTm[isub-1][l] = VTm[n-i][l];
        VTm[n-i][l] = tmp;
      }
    }
  }
  __syncthreads();
  // ormbr('P','R','T')
  for (int i = n-2; i >= 0; i--){
    float tp = taup[i];
    if (tp != 0.f && l < 16){
      int r = l;
      float w = VTm[r][i+1];
      for (int c = i+2; c < n; c++) w += VTm[r][c]*A[i][c];
      w *= tp;
      VTm[r][i+1] -= w;
      for (int c = i+2; c < n; c++) VTm[r][c] -= w*A[i][c];
    }
    __syncthreads();
  }
  for (int idx = l; idx < 256; idx += 64) vtlOut[idx] = VTm[idx>>4][idx&15];
}
#undef Dv
#undef Ev

// K12: R = Qqr * VT_L^T ; Rinv = R^T
__global__ __launch_bounds__(256) void k_rout(float* __restrict__ ws, float* __restrict__ out){
  int ty = blockIdx.y;
  const float* Qq = ws + OFF_QQR + (size_t)ty*65536;
  const float* vtl = ws + OFF_VTL + ty*256;
  long long Roff  = ty ? OUT_R2  : OUT_R1;
  long long RIoff = ty ? OUT_RI2 : OUT_RI1;
  __shared__ float V[16][16];
  int t = threadIdx.x;
  V[t>>4][t&15] = vtl[t];
  __syncthreads();
  int row = blockIdx.x*256 + t;
  float mv[16];
  #pragma unroll
  for (int q = 0; q < 4; q++){
    float4 v = ((const float4*)(Qq + (size_t)row*16))[q];
    mv[q*4] = v.x; mv[q*4+1] = v.y; mv[q*4+2] = v.z; mv[q*4+3] = v.w;
  }
  #pragma unroll
  for (int j = 0; j < 16; j++){
    float s = 0.f;
    #pragma unroll
    for (int i = 0; i < 16; i++) s = fmaf(mv[i], V[j][i], s);
    out[Roff + (long long)row*16 + j] = s;
    out[RIoff + (long long)j*4096 + row] = s;
  }
}

// ===========================================================================
extern "C" void kernel_launch(void* const* d_in, const int* in_sizes, int n_in,
                              void* d_out, int out_size, void* d_ws, size_t ws_size,
                              hipStream_t stream){
  const float* x1 = (const float*)d_in[0];
  const float* x2 = (const float*)d_in[1];
  float* out = (float*)d_out;
  float* ws = (float*)d_ws;
  (void)in_sizes; (void)n_in; (void)out_size; (void)ws_size;

  // only the fine histogram (atomic target) needs zeroing: 8 MB
  hipMemsetAsync(d_ws, 0, (size_t)2097152*4, stream);

  // quantiles + hadamard
  k_hadamard_hist<<<dim3(512), 256, 0, stream>>>(x1, x2, out, ws);
  k_coarse_red<<<dim3(16, 2), 256, 0, stream>>>(ws);
  k_coarse_scan<<<dim3(2), 256, 0, stream>>>(ws);
  k_fine_hist<<<dim3(1024, 2), 256, 0, stream>>>(x1, x2, ws);
  k_seg_sum<<<dim3(1024, 2), 256, 0, stream>>>(ws);
  k_fine_scan2<<<dim3(2), 256, 0, stream>>>(ws, out);

  // keys: foldlike split of key(42) = (0,42)
  uint32_t a0, a1, b0, b1;
  h_threefry(0u, 42u, 0u, 0u, a0, a1);
  h_threefry(0u, 42u, 0u, 1u, b0, b1);
  k_omega<<<dim3(256, 2), 256, 0, stream>>>(a0, a1, b0, b1, ws);

  // QR1: Y0 = res*Omega -> Q0
  k_atype<<<dim3(512, 2), 256, 0, stream>>>(x1, x2, ws, OFF_OMT);
  k_gramP<<<dim3(64, 2), 256, 0, stream>>>(ws, OFF_BIGY, 131072);
  k_tiny<<<dim3(2), 64, 0, stream>>>(ws, OFF_BIGY, 131072);
  k_applyq<<<dim3(32, 2), 256, 0, stream>>>(ws, OFF_BIGY, 131072, OFF_BIGQ, 131072, 8192, 1, 0);
  // QR2: T = res^T*Q0 -> Z1 (as Z1^T)
  k_btype<<<dim3(256, 2), 256, 0, stream>>>(x1, x2, ws);
  k_bredgram<<<dim3(64, 2), 256, 0, stream>>>(ws);
  k_tiny<<<dim3(2), 64, 0, stream>>>(ws, OFF_TMAT, 65536);
  k_applyq<<<dim3(16, 2), 256, 0, stream>>>(ws, OFF_TMAT, 65536, OFF_ZT, 65536, 4096, 0, 1);
  // QR3: Y1 = res*Z1 -> Q1
  k_atype<<<dim3(512, 2), 256, 0, stream>>>(x1, x2, ws, OFF_ZT);
  k_gramP<<<dim3(64, 2), 256, 0, stream>>>(ws, OFF_BIGY, 131072);
  k_tiny<<<dim3(2), 64, 0, stream>>>(ws, OFF_BIGY, 131072);
  k_applyq<<<dim3(32, 2), 256, 0, stream>>>(ws, OFF_BIGY, 131072, OFF_BIGQ, 131072, 8192, 1, 0);
  // QR4: T = res^T*Q1 -> Z2 (as Z2^T)
  k_btype<<<dim3(256, 2), 256, 0, stream>>>(x1, x2, ws);
  k_bredgram<<<dim3(64, 2), 256, 0, stream>>>(ws);
  k_tiny<<<dim3(2), 64, 0, stream>>>(ws, OFF_TMAT, 65536);
  k_applyq<<<dim3(16, 2), 256, 0, stream>>>(ws, OFF_TMAT, 65536, OFF_ZT, 65536, 4096, 0, 1);
  // QR5: Y2 = res*Z2 -> Q2
  k_atype<<<dim3(512, 2), 256, 0, stream>>>(x1, x2, ws, OFF_ZT);
  k_gramP<<<dim3(64, 2), 256, 0, stream>>>(ws, OFF_BIGY, 131072);
  k_tiny<<<dim3(2), 64, 0, stream>>>(ws, OFF_BIGY, 131072);
  k_applyq<<<dim3(32, 2), 256, 0, stream>>>(ws, OFF_BIGY, 131072, OFF_BIGQ, 131072, 8192, 1, 0);
  // QR6: B^T = res^T*Q2 ; geqrf(B^T) == gelqf(B) -> Qqr, Rg
  k_btype<<<dim3(256, 2), 256, 0, stream>>>(x1, x2, ws);
  k_bredgram<<<dim3(64, 2), 256, 0, stream>>>(ws);
  k_tiny<<<dim3(2), 64, 0, stream>>>(ws, OFF_TMAT, 65536);
  k_applyq<<<dim3(16, 2), 256, 0, stream>>>(ws, OFF_TMAT, 65536, OFF_QQR, 65536, 4096, 1, 0);

  // 16x16 gesdd tail + final output GEMM
  k_chain<<<dim3(2), 64, 0, stream>>>(ws);
  k_rout<<<dim3(16, 2), 256, 0, stream>>>(ws, out);
}

// Round 3
// 1636.047 us; speedup vs baseline: 1.9358x; 1.0436x over previous
//
#include <hip/hip_runtime.h>
#include <cstdint>
#include <cstddef>

// ============================================================================
// EfficientMemoryHadamard — round 3.
//  R1: atomic-free GEMM partials (r2). R3: register-resident bdsqr/geqrf,
//  speculative fused fine-quantile histogram.
// Verified assumption stack (rounds 1-2 PASSED, absmax 0.1245):
//  A1: jax threefry_partitionable; A2: quantile = order stat 33218888;
//  A3: gesdd tail gelqf->gebd2->bdsqr->ormbr; A4: LAPACK>=3.10 slartg.
// ============================================================================

#define DEV __device__ __forceinline__

constexpr long long NTOT = 33554432LL;
constexpr unsigned long long KSEL = 33218888ULL;

constexpr long long OUT_T1  = 33554432LL;
constexpr long long OUT_R1  = 33554433LL;
constexpr long long OUT_RI1 = 33619969LL;
constexpr long long OUT_T2  = 33685505LL;
constexpr long long OUT_R2  = 33685506LL;
constexpr long long OUT_RI2 = 33751042LL;

// ---- workspace layout (float units) ----
constexpr size_t OFF_SPEC   = 0;         // 2 x 2M u32 speculative fine hist (zeroed)
constexpr size_t OFF_BPART  = 0;         // alias: 2*16*65536 floats (after quantile)
constexpr size_t OFF_FB     = 4194304;   // 2 x 1M u32 fallback fine hist (zeroed)
constexpr size_t ZERO_FLOATS= 6291456;   // 24 MB memset
constexpr size_t OFF_CHIST  = 6291456;   // 512*2*2048 u32 partial coarse hists
constexpr size_t OFF_COARSE = 8388608;   // 2*2048 u32
constexpr size_t OFF_SEGS   = 8392704;   // 2*1024 u32
constexpr size_t OFF_SELR   = 8394752;   // 2*4 ints (bin, rank, valid)
constexpr size_t OFF_TSEL   = 8394768;   // 2 floats (+pad)
constexpr size_t OFF_OMT    = 8394784;   // 2*65536
constexpr size_t OFF_BIGY   = 8525856;   // 2*131072
constexpr size_t OFF_BIGQ   = 8788000;   // 2*131072
constexpr size_t OFF_ZT     = 9050144;   // 2*65536
constexpr size_t OFF_QQR    = 9181216;   // 2*65536
constexpr size_t OFF_TMAT   = 9312288;   // 2*65536
constexpr size_t OFF_GRAMP  = 9443360;   // 2*64*256
constexpr size_t OFF_S      = 9476128;   // 2*256
constexpr size_t OFF_QTOP   = 9476640;   // 2*256
constexpr size_t OFF_RG     = 9477152;   // 2*256
constexpr size_t OFF_VTL    = 9477664;   // 2*256
// total 9478176 floats ~= 37.9 MB

// ---------------------------------------------------------------------------
#define TFR(a,b,r) { a += b; b = (b << r) | (b >> (32 - r)); b ^= a; }

DEV void d_threefry(uint32_t k0, uint32_t k1, uint32_t x0, uint32_t x1,
                    uint32_t& o0, uint32_t& o1){
  uint32_t ks2 = k0 ^ k1 ^ 0x1BD11BDAu;
  x0 += k0; x1 += k1;
  TFR(x0,x1,13) TFR(x0,x1,15) TFR(x0,x1,26) TFR(x0,x1,6)
  x0 += k1; x1 += ks2 + 1u;
  TFR(x0,x1,17) TFR(x0,x1,29) TFR(x0,x1,16) TFR(x0,x1,24)
  x0 += ks2; x1 += k0 + 2u;
  TFR(x0,x1,13) TFR(x0,x1,15) TFR(x0,x1,26) TFR(x0,x1,6)
  x0 += k0; x1 += k1 + 3u;
  TFR(x0,x1,17) TFR(x0,x1,29) TFR(x0,x1,16) TFR(x0,x1,24)
  x0 += k1; x1 += ks2 + 4u;
  TFR(x0,x1,13) TFR(x0,x1,15) TFR(x0,x1,26) TFR(x0,x1,6)
  x0 += ks2; x1 += k0 + 5u;
  o0 = x0; o1 = x1;
}

static void h_threefry(uint32_t k0, uint32_t k1, uint32_t x0, uint32_t x1,
                       uint32_t& o0, uint32_t& o1){
  uint32_t ks2 = k0 ^ k1 ^ 0x1BD11BDAu;
  x0 += k0; x1 += k1;
  TFR(x0,x1,13) TFR(x0,x1,15) TFR(x0,x1,26) TFR(x0,x1,6)
  x0 += k1; x1 += ks2 + 1u;
  TFR(x0,x1,17) TFR(x0,x1,29) TFR(x0,x1,16) TFR(x0,x1,24)
  x0 += ks2; x1 += k0 + 2u;
  TFR(x0,x1,13) TFR(x0,x1,15) TFR(x0,x1,26) TFR(x0,x1,6)
  x0 += k0; x1 += k1 + 3u;
  TFR(x0,x1,17) TFR(x0,x1,29) TFR(x0,x1,16) TFR(x0,x1,24)
  x0 += k1; x1 += ks2 + 4u;
  TFR(x0,x1,13) TFR(x0,x1,15) TFR(x0,x1,26) TFR(x0,x1,6)
  x0 += ks2; x1 += k0 + 5u;
  o0 = x0; o1 = x1;
}

DEV float erfinv_f32(float x){
  float w = -log1pf(-x*x);
  float p;
  if (w < 5.0f){
    w -= 2.5f;
    p = 2.81022636e-08f;
    p = fmaf(p, w, 3.43273939e-07f);
    p = fmaf(p, w, -3.5233877e-06f);
    p = fmaf(p, w, -4.39150654e-06f);
    p = fmaf(p, w, 0.00021858087f);
    p = fmaf(p, w, -0.00125372503f);
    p = fmaf(p, w, -0.00417768164f);
    p = fmaf(p, w, 0.246640727f);
    p = fmaf(p, w, 1.50140941f);
  } else {
    w = sqrtf(w) - 3.0f;
    p = -0.000200214257f;
    p = fmaf(p, w, 0.000100950558f);
    p = fmaf(p, w, 0.00134934322f);
    p = fmaf(p, w, -0.00367342844f);
    p = fmaf(p, w, 0.00573950773f);
    p = fmaf(p, w, -0.0076224613f);
    p = fmaf(p, w, 0.00943887047f);
    p = fmaf(p, w, 1.00167406f);
    p = fmaf(p, w, 2.83297682f);
  }
  return p * x;
}

DEV float lapy2f(float x, float y){
  float xa = fabsf(x), ya = fabsf(y);
  float w = fmaxf(xa, ya), z = fminf(xa, ya);
  if (z == 0.f) return w;
  float q = z / w;
  return w * sqrtf(1.f + q*q);
}

DEV void slartg_(float f, float g, float& c, float& s, float& r){
  if (g == 0.f){ c = 1.f; s = 0.f; r = f; }
  else if (f == 0.f){ c = 0.f; s = copysignf(1.f, g); r = fabsf(g); }
  else {
    float d = sqrtf(f*f + g*g);
    c = fabsf(f) / d;
    r = copysignf(d, f);
    s = g / r;
  }
}

DEV void slas2_(float f, float g, float h, float& ssmin, float& ssmax){
  float fa = fabsf(f), ga = fabsf(g), ha = fabsf(h);
  float fhmn = fminf(fa, ha), fhmx = fmaxf(fa, ha);
  if (fhmn == 0.f){
    ssmin = 0.f;
    if (fhmx == 0.f) ssmax = ga;
    else {
      float mx = fmaxf(fhmx, ga), mn = fminf(fhmx, ga);
      float q = mn/mx;
      ssmax = mx*sqrtf(1.f + q*q);
    }
  } else {
    if (ga < fhmx){
      float as_ = 1.f + fhmn/fhmx;
      float at_ = (fhmx - fhmn)/fhmx;
      float au = ga/fhmx; au = au*au;
      float cc = 2.f/(sqrtf(as_*as_ + au) + sqrtf(at_*at_ + au));
      ssmin = fhmn*cc; ssmax = fhmx/cc;
    } else {
      float au = fhmx/ga;
      if (au == 0.f){ ssmin = (fhmn*fhmx)/ga; ssmax = ga; }
      else {
        float as_ = 1.f + fhmn/fhmx;
        float at_ = (fhmx - fhmn)/fhmx;
        float q1 = as_*au, q2 = at_*au;
        float cc = 1.f/(sqrtf(1.f + q1*q1) + sqrtf(1.f + q2*q2));
        ssmin = (fhmn*cc)*au; ssmin = ssmin + ssmin;
        ssmax = ga/(cc + cc);
      }
    }
  }
}

DEV void slasv2_(float f, float g, float h, float& ssmin, float& ssmax,
                 float& snr, float& csr, float& snl, float& csl){
  const float eps = 5.9604645e-08f;
  float ft = f, fa = fabsf(f), ht = h, ha = fabsf(h);
  int pmax = 1;
  bool swp = (ha > fa);
  if (swp){ pmax = 3; float t; t=ft; ft=ht; ht=t; t=fa; fa=ha; ha=t; }
  float gt = g, ga = fabsf(g);
  float clt = 0.f, crt = 0.f, slt = 0.f, srt = 0.f;
  if (ga == 0.f){ ssmin = ha; ssmax = fa; clt = 1.f; crt = 1.f; slt = 0.f; srt = 0.f; }
  else {
    bool gasmal = true;
    if (ga > fa){
      pmax = 2;
      if ((fa/ga) < eps){
        gasmal = false;
        ssmax = ga;
        if (ha > 1.f) ssmin = fa/(ga/ha); else ssmin = (fa/ga)*ha;
        clt = 1.f; slt = ht/gt; srt = 1.f; crt = ft/gt;
      }
    }
    if (gasmal){
      float dd = fa - ha;
      float L = (dd == fa) ? 1.f : dd/fa;
      float Mv = gt/ft;
      float T = 2.f - L;
      float MM = Mv*Mv, TT = T*T;
      float Sv = sqrtf(TT + MM);
      float Rv = (L == 0.f) ? fabsf(Mv) : sqrtf(L*L + MM);
      float Av = 0.5f*(Sv + Rv);
      ssmin = ha/Av; ssmax = fa*Av;
      float Tv;
      if (MM == 0.f){
        if (L == 0.f) Tv = copysignf(2.f, ft)*copysignf(1.f, gt);
        else Tv = gt/copysignf(dd, ft) + Mv/T;
      } else {
        Tv = (Mv/(Sv + T) + Mv/(Rv + L))*(1.f + Av);
      }
      float Lv = sqrtf(Tv*Tv + 4.f);
      crt = 2.f/Lv; srt = Tv/Lv;
      clt = (crt + srt*Mv)/Av;
      slt = (ht/ft)*srt/Av;
    }
  }
  if (swp){ csl = srt; snl = crt; csr = slt; snr = clt; }
  else    { csl = clt; snl = slt; csr = crt; snr = srt; }
  float tsign = 1.f;
  if (pmax == 1) tsign = copysignf(1.f, csr)*copysignf(1.f, csl)*copysignf(1.f, f);
  if (pmax == 2) tsign = copysignf(1.f, snr)*copysignf(1.f, csl)*copysignf(1.f, g);
  if (pmax == 3) tsign = copysignf(1.f, snr)*copysignf(1.f, snl)*copysignf(1.f, h);
  ssmax = copysignf(ssmax, tsign);
  ssmin = copysignf(ssmin, tsign*copysignf(1.f, f)*copysignf(1.f, h));
}

// ===========================================================================
// K1: hadamard + 4-way replicated LDS coarse hists + SPECULATIVE fine hist
//     (exact 20-bit histogram for coarse bins 0x401,0x402 == |x| in [2.25,2.75))
// ===========================================================================
__global__ __launch_bounds__(256) void k_hadamard_hist(const float* __restrict__ x1,
    const float* __restrict__ x2, float* __restrict__ out, float* __restrict__ ws){
  __shared__ uint32_t lh[2][4][2048];
  for (int i = threadIdx.x; i < 2*4*2048; i += 256) (&lh[0][0][0])[i] = 0u;
  __syncthreads();
  int rep = threadIdx.x & 3;
  uint32_t* s1 = (uint32_t*)(ws + OFF_SPEC);
  uint32_t* s2 = s1 + 2097152;
  const float4* a4 = (const float4*)x1;
  const float4* b4 = (const float4*)x2;
  float4* o4 = (float4*)out;
  long long n4 = NTOT/4;
  long long stride = (long long)gridDim.x * 256;
  for (long long i = (long long)blockIdx.x*256 + threadIdx.x; i < n4; i += stride){
    float4 a = a4[i], b = b4[i];
    float4 o; o.x=a.x*b.x; o.y=a.y*b.y; o.z=a.z*b.z; o.w=a.w*b.w;
    o4[i] = o;
    uint32_t u, dd;
    u = __float_as_uint(a.x)&0x7fffffffu; atomicAdd(&lh[0][rep][u>>20], 1u);
    dd = u - 0x40100000u; if (dd < 0x200000u) atomicAdd(&s1[dd], 1u);
    u = __float_as_uint(a.y)&0x7fffffffu; atomicAdd(&lh[0][rep][u>>20], 1u);
    dd = u - 0x40100000u; if (dd < 0x200000u) atomicAdd(&s1[dd], 1u);
    u = __float_as_uint(a.z)&0x7fffffffu; atomicAdd(&lh[0][rep][u>>20], 1u);
    dd = u - 0x40100000u; if (dd < 0x200000u) atomicAdd(&s1[dd], 1u);
    u = __float_as_uint(a.w)&0x7fffffffu; atomicAdd(&lh[0][rep][u>>20], 1u);
    dd = u - 0x40100000u; if (dd < 0x200000u) atomicAdd(&s1[dd], 1u);
    u = __float_as_uint(b.x)&0x7fffffffu; atomicAdd(&lh[1][rep][u>>20], 1u);
    dd = u - 0x40100000u; if (dd < 0x200000u) atomicAdd(&s2[dd], 1u);
    u = __float_as_uint(b.y)&0x7fffffffu; atomicAdd(&lh[1][rep][u>>20], 1u);
    dd = u - 0x40100000u; if (dd < 0x200000u) atomicAdd(&s2[dd], 1u);
    u = __float_as_uint(b.z)&0x7fffffffu; atomicAdd(&lh[1][rep][u>>20], 1u);
    dd = u - 0x40100000u; if (dd < 0x200000u) atomicAdd(&s2[dd], 1u);
    u = __float_as_uint(b.w)&0x7fffffffu; atomicAdd(&lh[1][rep][u>>20], 1u);
    dd = u - 0x40100000u; if (dd < 0x200000u) atomicAdd(&s2[dd], 1u);
  }
  __syncthreads();
  uint32_t* ch = (uint32_t*)(ws + OFF_CHIST);
  for (int i = threadIdx.x; i < 2048; i += 256){
    uint32_t c0 = lh[0][0][i] + lh[0][1][i] + lh[0][2][i] + lh[0][3][i];
    uint32_t c1 = lh[1][0][i] + lh[1][1][i] + lh[1][2][i] + lh[1][3][i];
    ch[((size_t)blockIdx.x*2 + 0)*2048 + i] = c0;
    ch[((size_t)blockIdx.x*2 + 1)*2048 + i] = c1;
  }
}

__global__ __launch_bounds__(256) void k_coarse_red(float* __restrict__ ws){
  int ty = blockIdx.y;
  const uint32_t* ch = (const uint32_t*)(ws + OFF_CHIST);
  uint32_t* h = (uint32_t*)(ws + OFF_COARSE) + ty*2048;
  int bin = blockIdx.x*128 + (threadIdx.x & 127);
  int half = threadIdx.x >> 7;
  uint32_t s = 0;
  for (int p = half*256; p < half*256 + 256; p++)
    s += ch[((size_t)p*2 + ty)*2048 + bin];
  __shared__ uint32_t sh[256];
  sh[threadIdx.x] = s;
  __syncthreads();
  if (threadIdx.x < 128) h[bin] = sh[threadIdx.x] + sh[threadIdx.x + 128];
}

__global__ __launch_bounds__(256) void k_coarse_scan(float* __restrict__ ws){
  int ty = blockIdx.x;
  const uint32_t* h = (const uint32_t*)(ws + OFF_COARSE) + ty*2048;
  int* selr = (int*)(ws + OFF_SELR) + ty*4;
  __shared__ unsigned long long ps[256];
  unsigned long long s = 0;
  for (int j = 0; j < 8; j++) s += h[threadIdx.x*8 + j];
  ps[threadIdx.x] = s;
  __syncthreads();
  if (threadIdx.x == 0){
    unsigned long long cum = 0, K = KSEL;
    int g = 0;
    for (; g < 256; g++){ if (cum + ps[g] > K) break; cum += ps[g]; }
    if (g > 255) g = 255;
    int bin = 2047;
    for (int j = 0; j < 8; j++){
      uint32_t c = h[g*8 + j];
      if (cum + c > K){ bin = g*8 + j; break; }
      cum += c;
    }
    selr[0] = bin;
    selr[1] = (int)(K - cum);
    selr[2] = (bin >= 0x401 && bin <= 0x402) ? 1 : 0;  // speculative hist covers it?
  }
}

// fallback fine hist — early-exits when speculation valid (the normal case)
__global__ __launch_bounds__(256) void k_fine_fb(const float* __restrict__ x1,
    const float* __restrict__ x2, float* __restrict__ ws){
  int ty = blockIdx.y;
  const int* selr = (const int*)(ws + OFF_SELR) + ty*4;
  if (selr[2]) return;
  const float4* x4 = (const float4*)(ty ? x2 : x1);
  uint32_t bin = (uint32_t)selr[0];
  uint32_t* f = (uint32_t*)(ws + OFF_FB) + ((size_t)ty<<20);
  long long n4 = NTOT/4;
  long long stride = (long long)gridDim.x * 256;
  for (long long i = (long long)blockIdx.x*256 + threadIdx.x; i < n4; i += stride){
    float4 a = x4[i];
    uint32_t u;
    u = __float_as_uint(a.x)&0x7fffffffu; if ((u>>20)==bin) atomicAdd(&f[u&0xFFFFFu],1u);
    u = __float_as_uint(a.y)&0x7fffffffu; if ((u>>20)==bin) atomicAdd(&f[u&0xFFFFFu],1u);
    u = __float_as_uint(a.z)&0x7fffffffu; if ((u>>20)==bin) atomicAdd(&f[u&0xFFFFFu],1u);
    u = __float_as_uint(a.w)&0x7fffffffu; if ((u>>20)==bin) atomicAdd(&f[u&0xFFFFFu],1u);
  }
}

DEV const uint32_t* fine_base(const float* ws, int ty){
  const int* selr = (const int*)(ws + OFF_SELR) + ty*4;
  if (selr[2])
    return (const uint32_t*)(ws + OFF_SPEC) + ((size_t)ty<<21)
           + (((uint32_t)selr[0] - 0x401u) << 20);
  return (const uint32_t*)(ws + OFF_FB) + ((size_t)ty<<20);
}

__global__ __launch_bounds__(256) void k_seg_sum(float* __restrict__ ws){
  int ty = blockIdx.y;
  const uint32_t* f = fine_base(ws, ty);
  uint32_t* segs = (uint32_t*)(ws + OFF_SEGS) + ty*1024;
  uint32_t s = 0;
  int base = blockIdx.x*1024;
  for (int k = 0; k < 4; k++) s += f[base + k*256 + threadIdx.x];
  __shared__ uint32_t sh[256];
  sh[threadIdx.x] = s;
  __syncthreads();
  for (int off = 128; off > 0; off >>= 1){
    if (threadIdx.x < off) sh[threadIdx.x] += sh[threadIdx.x + off];
    __syncthreads();
  }
  if (threadIdx.x == 0) segs[blockIdx.x] = sh[0];
}

__global__ __launch_bounds__(256) void k_fine_scan2(float* __restrict__ ws, float* __restrict__ out){
  int ty = blockIdx.x;
  const uint32_t* f = fine_base(ws, ty);
  const uint32_t* segs = (const uint32_t*)(ws + OFF_SEGS) + ty*1024;
  const int* selr = (const int*)(ws + OFF_SELR) + ty*4;
  __shared__ uint32_t sh[1024];
  __shared__ uint32_t ps[256];
  __shared__ int gsel; __shared__ uint32_t csel;
  int t = threadIdx.x;
  uint32_t K = (uint32_t)selr[1];
  for (int k = 0; k < 4; k++) sh[k*256 + t] = segs[k*256 + t];
  __syncthreads();
  ps[t] = sh[4*t] + sh[4*t+1] + sh[4*t+2] + sh[4*t+3];
  __syncthreads();
  if (t == 0){
    uint32_t cum = 0; int q = 0;
    for (; q < 256; q++){ if (cum + ps[q] > K) break; cum += ps[q]; }
    if (q > 255) q = 255;
    int g = q*4;
    for (int j = 0; j < 4; j++){
      uint32_t c = sh[q*4 + j];
      if (cum + c > K){ g = q*4 + j; break; }
      cum += c;
      if (j == 3) g = q*4 + 3;
    }
    gsel = g; csel = cum;
  }
  __syncthreads();
  int g = gsel;
  for (int k = 0; k < 4; k++) sh[k*256 + t] = f[(size_t)g*1024 + k*256 + t];
  __syncthreads();
  ps[t] = sh[4*t] + sh[4*t+1] + sh[4*t+2] + sh[4*t+3];
  __syncthreads();
  if (t == 0){
    uint32_t cum = csel; int q = 0;
    for (; q < 256; q++){ if (cum + ps[q] > K) break; cum += ps[q]; }
    if (q > 255) q = 255;
    int j = q*4 + 3;
    for (int jj = 0; jj < 4; jj++){
      uint32_t c = sh[q*4 + jj];
      if (cum + c > K){ j = q*4 + jj; break; }
      cum += c;
    }
    uint32_t bits = (((uint32_t)selr[0])<<20) | (uint32_t)((g*1024 + j) & 0xFFFFF);
    float th = __uint_as_float(bits);
    ws[OFF_TSEL + ty] = th;
    out[ty ? OUT_T2 : OUT_T1] = th;
  }
}

__global__ __launch_bounds__(256) void k_omega(uint32_t a0, uint32_t a1,
    uint32_t b0, uint32_t b1, float* __restrict__ ws){
  int ty = blockIdx.y;
  uint32_t k0 = ty ? b0 : a0, k1 = ty ? b1 : a1;
  int i = blockIdx.x*256 + threadIdx.x;
  uint32_t o0, o1;
  d_threefry(k0, k1, 0u, (uint32_t)i, o0, o1);
  uint32_t bits = o0 ^ o1;
  float fr = __uint_as_float((bits >> 9) | 0x3f800000u) - 1.0f;
  const float lo = -0.99999994f;
  float u = fr * 2.0f + lo;
  u = fmaxf(lo, u);
  float v = 1.41421356237f * erfinv_f32(u);
  int row = i >> 4, col = i & 15;
  ws[OFF_OMT + (size_t)ty*65536 + (size_t)col*4096 + row] = v;
}

// K6: Y(8192x16) = residual(x) * W  (W^T 16x4096 in ws)
__global__ __launch_bounds__(256) void k_atype(const float* __restrict__ x1,
    const float* __restrict__ x2, float* __restrict__ ws, size_t wtOff){
  int ty = blockIdx.y;
  const float* x = ty ? x2 : x1;
  const float* wt = ws + wtOff + (size_t)ty*65536;
  float* Y = ws + OFF_BIGY + (size_t)ty*131072;
  float t = ws[OFF_TSEL + ty];
  int wave = threadIdx.x >> 6, lane = threadIdx.x & 63;
  __shared__ __align__(16) float wts[16][256];
  __shared__ float outs[16][16];
  float acc[4][16];
  #pragma unroll
  for (int r = 0; r < 4; r++)
    #pragma unroll
    for (int j = 0; j < 16; j++) acc[r][j] = 0.f;
  int rowbase = blockIdx.x*16 + wave*4;
  for (int c = 0; c < 4096; c += 256){
    __syncthreads();
    for (int idx = threadIdx.x; idx < 16*64; idx += 256){
      int j = idx >> 6, q = idx & 63;
      ((float4*)&wts[j][0])[q] = ((const float4*)(wt + (size_t)j*4096 + c))[q];
    }
    __syncthreads();
    float4 xv[4];
    #pragma unroll
    for (int rr = 0; rr < 4; rr++){
      int row = rowbase + rr;
      float4 a = ((const float4*)(x + (size_t)row*4096 + c))[lane];
      a.x = fabsf(a.x) > t ? 0.f : a.x;
      a.y = fabsf(a.y) > t ? 0.f : a.y;
      a.z = fabsf(a.z) > t ? 0.f : a.z;
      a.w = fabsf(a.w) > t ? 0.f : a.w;
      xv[rr] = a;
    }
    #pragma unroll
    for (int j = 0; j < 16; j++){
      float4 w4 = ((const float4*)&wts[j][0])[lane];
      #pragma unroll
      for (int rr = 0; rr < 4; rr++){
        acc[rr][j] = fmaf(xv[rr].x, w4.x, acc[rr][j]);
        acc[rr][j] = fmaf(xv[rr].y, w4.y, acc[rr][j]);
        acc[rr][j] = fmaf(xv[rr].z, w4.z, acc[rr][j]);
        acc[rr][j] = fmaf(xv[rr].w, w4.w, acc[rr][j]);
      }
    }
  }
  #pragma unroll
  for (int rr = 0; rr < 4; rr++)
    for (int j = 0; j < 16; j++){
      float v = acc[rr][j];
      for (int off = 32; off > 0; off >>= 1) v += __shfl_xor(v, off, 64);
      if (lane == 0) outs[wave*4 + rr][j] = v;
    }
  __syncthreads();
  int r = threadIdx.x >> 4, cc = threadIdx.x & 15;
  Y[(size_t)(blockIdx.x*16 + r)*16 + cc] = outs[r][cc];
}

__global__ __launch_bounds__(256) void k_gramP(float* __restrict__ ws, size_t mOff,
    size_t mStr){
  int ty = blockIdx.y;
  const float* M = ws + mOff + (size_t)ty*mStr;
  float* gp = ws + OFF_GRAMP + (size_t)(ty*64 + blockIdx.x)*256;
  __shared__ __align__(16) float buf[128][16];
  int t = threadIdx.x;
  for (int q = t; q < 512; q += 256)
    ((float4*)&buf[0][0])[q] = ((const float4*)(M + (size_t)blockIdx.x*2048))[q];
  __syncthreads();
  int i = t >> 4, j = t & 15;
  float s = 0.f;
  int rstart = (blockIdx.x == 0) ? 16 : 0;
  for (int r = rstart; r < 128; r++) s += buf[r][i]*buf[r][j];
  gp[t] = s;
}

__global__ __launch_bounds__(256) void k_btype(const float* __restrict__ x1,
    const float* __restrict__ x2, float* __restrict__ ws){
  int ty = blockIdx.y;
  const float* x = ty ? x2 : x1;
  const float* Q = ws + OFF_BIGQ + (size_t)ty*131072;
  float t = ws[OFF_TSEL + ty];
  int cb = blockIdx.x & 15;
  int rc = blockIdx.x >> 4;
  int c = cb*256 + threadIdx.x;
  int r0 = rc*512;
  __shared__ __align__(16) float Qs[64][16];
  float acc[16];
  #pragma unroll
  for (int j = 0; j < 16; j++) acc[j] = 0.f;
  for (int tile = 0; tile < 8; tile++){
    __syncthreads();
    ((float4*)&Qs[0][0])[threadIdx.x] =
        ((const float4*)(Q + (size_t)(r0 + tile*64)*16))[threadIdx.x];
    __syncthreads();
    const float* xp = x + (size_t)(r0 + tile*64)*4096 + c;
    #pragma unroll 4
    for (int rr = 0; rr < 64; rr++){
      float v = xp[(size_t)rr*4096];
      v = fabsf(v) > t ? 0.f : v;
      float4 qa = ((const float4*)&Qs[rr][0])[0];
      float4 qb = ((const float4*)&Qs[rr][0])[1];
      float4 qc = ((const float4*)&Qs[rr][0])[2];
      float4 qd = ((const float4*)&Qs[rr][0])[3];
      acc[ 0] = fmaf(v, qa.x, acc[ 0]);
      acc[ 1] = fmaf(v, qa.y, acc[ 1]);
      acc[ 2] = fmaf(v, qa.z, acc[ 2]);
      acc[ 3] = fmaf(v, qa.w, acc[ 3]);
      acc[ 4] = fmaf(v, qb.x, acc[ 4]);
      acc[ 5] = fmaf(v, qb.y, acc[ 5]);
      acc[ 6] = fmaf(v, qb.z, acc[ 6]);
      acc[ 7] = fmaf(v, qb.w, acc[ 7]);
      acc[ 8] = fmaf(v, qc.x, acc[ 8]);
      acc[ 9] = fmaf(v, qc.y, acc[ 9]);
      acc[10] = fmaf(v, qc.z, acc[10]);
      acc[11] = fmaf(v, qc.w, acc[11]);
      acc[12] = fmaf(v, qd.x, acc[12]);
      acc[13] = fmaf(v, qd.y, acc[13]);
      acc[14] = fmaf(v, qd.z, acc[14]);
      acc[15] = fmaf(v, qd.w, acc[15]);
    }
  }
  float* BP = ws + OFF_BPART + (((size_t)(ty*16 + rc))<<16) + (size_t)c*16;
  #pragma unroll
  for (int q = 0; q < 4; q++){
    float4 o; o.x = acc[q*4]; o.y = acc[q*4+1]; o.z = acc[q*4+2]; o.w = acc[q*4+3];
    ((float4*)BP)[q] = o;
  }
}

__global__ __launch_bounds__(256) void k_bredgram(float* __restrict__ ws){
  int ty = blockIdx.y;
  const float* BP = ws + OFF_BPART + (((size_t)ty*16)<<16);
  float* T = ws + OFF_TMAT + (size_t)ty*65536;
  float* gp = ws + OFF_GRAMP + (size_t)(ty*64 + blockIdx.x)*256;
  __shared__ float sh[64][16];
  int t = threadIdx.x;
  for (int k = 0; k < 4; k++){
    int e = blockIdx.x*1024 + k*256 + t;
    float s = 0.f;
    #pragma unroll
    for (int rc = 0; rc < 16; rc++) s += BP[((size_t)rc<<16) + e];
    T[e] = s;
    int le = k*256 + t;
    sh[le >> 4][le & 15] = s;
  }
  __syncthreads();
  int i = t >> 4, j = t & 15;
  float s = 0.f;
  int rstart = (blockIdx.x == 0) ? 16 : 0;
  for (int r = rstart; r < 64; r++) s += sh[r][i]*sh[r][j];
  gp[t] = s;
}

// K9: register-resident tiny QR: gram-sum, chol (LDS), geqrf+org2r (regs),
//     back-solve. Lane j<16 holds column j.
__global__ __launch_bounds__(64) void k_tiny(float* __restrict__ ws, size_t mOff,
    size_t mStr){
  int ty = blockIdx.x;
  const float* Mp = ws + mOff + (size_t)ty*mStr;
  float* sOut = ws + OFF_S + ty*256;
  float* qtOut = ws + OFF_QTOP + ty*256;
  float* rgOut = ws + OFF_RG + ty*256;
  __shared__ float G[16][16];
  __shared__ float Cld[32][16];
  __shared__ float bc[4];
  __shared__ float tau[16];
  int l = threadIdx.x;
  int j = l & 15;
  for (int e = l; e < 256; e += 64){
    const float* gp = ws + OFF_GRAMP + (size_t)ty*16384 + e;
    float s = 0.f;
    for (int p = 0; p < 64; p++) s += gp[(size_t)p*256];
    G[e>>4][e&15] = s;
  }
  for (int idx = l; idx < 256; idx += 64)
    Cld[idx>>4][idx&15] = Mp[idx];
  __syncthreads();
  // cholesky (upper) in place — identical op order to rounds 1-2
  for (int k = 0; k < 16; k++){
    float dk = sqrtf(G[k][k]);
    if (l == k) G[k][k] = dk;
    else if (l > k && l < 16) G[k][l] = G[k][l] / dk;
    __syncthreads();
    if (l > k && l < 16)
      for (int jj = l; jj < 16; jj++) G[l][jj] -= G[k][l]*G[k][jj];
    __syncthreads();
  }
  // build column registers: C = [M_top ; R_B]
  float Cc[32];
  #pragma unroll
  for (int r = 0; r < 32; r++){
    if (r < 16) Cc[r] = Cld[r][j];
    else Cc[r] = (j >= r - 16) ? G[r-16][j] : 0.f;
  }
  // geqrf (same arithmetic order as LDS version)
  #pragma unroll
  for (int i = 0; i < 16; i++){
    if (l == i){
      float alpha = Cc[i];
      float ssum = 0.f;
      #pragma unroll
      for (int r = i+1; r < 32; r++) ssum += Cc[r]*Cc[r];
      float xn = sqrtf(ssum);
      float beta, tv, sc;
      if (xn == 0.f){ tv = 0.f; beta = alpha; sc = 1.f; }
      else {
        beta = -copysignf(lapy2f(alpha, xn), alpha);
        tv = (beta - alpha)/beta;
        sc = 1.f/(alpha - beta);
        #pragma unroll
        for (int r = i+1; r < 32; r++) Cc[r] *= sc;
      }
      Cc[i] = beta;
      bc[0] = beta; bc[1] = tv;
      tau[i] = tv;
      #pragma unroll
      for (int r = i; r < 32; r++) Cld[r][i] = Cc[r];
    }
    __syncthreads();
    float tv = bc[1];
    if (tv != 0.f && l < 16 && j > i){
      float w = Cc[i];
      #pragma unroll
      for (int r = i+1; r < 32; r++) w += Cld[r][i]*Cc[r];
      w *= tv;
      Cc[i] -= w;
      #pragma unroll
      for (int r = i+1; r < 32; r++) Cc[r] -= w*Cld[r][i];
    }
    __syncthreads();
  }
  // org2r (no barriers needed: Cld/tau now read-only)
  float Qc[32];
  #pragma unroll
  for (int r = 0; r < 32; r++) Qc[r] = 0.f;
  #pragma unroll
  for (int i = 15; i >= 0; i--){
    float tv = tau[i];
    if (i < 15 && l < 16 && j > i){
      float w = Qc[i];
      #pragma unroll
      for (int r = i+1; r < 32; r++) w += Cld[r][i]*Qc[r];
      w *= tv;
      Qc[i] -= w;
      #pragma unroll
      for (int r = i+1; r < 32; r++) Qc[r] -= w*Cld[r][i];
    }
    if (l == i){
      #pragma unroll
      for (int r = 0; r < 32; r++){
        if (r < i) Qc[r] = 0.f;
        else if (r == i) Qc[r] = 1.f - tv;
        else Qc[r] = -tv * Cld[r][i];
      }
    }
  }
  // back-solve S = R_B^{-1} * Q_bot
  float Sc[16];
  if (l < 16){
    #pragma unroll
    for (int i2 = 15; i2 >= 0; i2--){
      float v = Qc[16 + i2];
      #pragma unroll
      for (int k2 = i2+1; k2 < 16; k2++) v -= G[i2][k2]*Sc[k2];
      Sc[i2] = v / G[i2][i2];
    }
    #pragma unroll
    for (int r = 0; r < 16; r++){
      rgOut[r*16 + j] = (j >= r) ? Cc[r] : 0.f;
      sOut[r*16 + j] = Sc[r];
      qtOut[r*16 + j] = Qc[r];
    }
  }
}

__global__ __launch_bounds__(256) void k_applyq(float* __restrict__ ws, size_t mOff,
    size_t mStr, size_t oOff, size_t oStr, int nrows, int wN, int wT){
  int ty = blockIdx.y;
  const float* Mp = ws + mOff + (size_t)ty*mStr;
  const float* sP = ws + OFF_S + ty*256;
  const float* qtP = ws + OFF_QTOP + ty*256;
  float* oP = ws + oOff + (size_t)ty*oStr;
  __shared__ float Ss[16][16], Qt[16][16];
  int t = threadIdx.x;
  Ss[t>>4][t&15] = sP[t];
  Qt[t>>4][t&15] = qtP[t];
  __syncthreads();
  int row = blockIdx.x*256 + t;
  if (row >= nrows) return;
  float o[16];
  if (row < 16){
    #pragma unroll
    for (int j = 0; j < 16; j++) o[j] = Qt[row][j];
  } else {
    float mv[16];
    #pragma unroll
    for (int q = 0; q < 4; q++){
      float4 v = ((const float4*)(Mp + (size_t)row*16))[q];
      mv[q*4] = v.x; mv[q*4+1] = v.y; mv[q*4+2] = v.z; mv[q*4+3] = v.w;
    }
    #pragma unroll
    for (int j = 0; j < 16; j++){
      float sacc = 0.f;
      #pragma unroll
      for (int i = 0; i < 16; i++) sacc = fmaf(mv[i], Ss[i][j], sacc);
      o[j] = sacc;
    }
  }
  if (wN){
    #pragma unroll
    for (int q = 0; q < 4; q++){
      float4 v; v.x = o[q*4]; v.y = o[q*4+1]; v.z = o[q*4+2]; v.w = o[q*4+3];
      ((float4*)(oP + (size_t)row*16))[q] = v;
    }
  }
  if (wT){
    #pragma unroll
    for (int j = 0; j < 16; j++) oP[(size_t)j*4096 + row] = o[j];
  }
}

// ===========================================================================
// K11: gesdd tail. gebd2 (LDS) -> bdsqr (REGISTERS, lane=VT column) -> ormbr.
// ===========================================================================
__global__ __launch_bounds__(64) void k_chain(float* __restrict__ ws){
  int ty = blockIdx.x;
  const float* rg = ws + OFF_RG + ty*256;
  float* vtlOut = ws + OFF_VTL + ty*256;
  const int n = 16;
  __shared__ float A[16][16];
  __shared__ float VTm[16][16];
  __shared__ float d_[16], e_[16], tauq[16], taup[16];
  int l = threadIdx.x;
  for (int idx = l; idx < 256; idx += 64){
    int r = idx >> 4, c = idx & 15;
    A[r][c] = (r >= c) ? rg[c*16 + r] : 0.f;   // L = Rg^T
  }
  __syncthreads();
  // ---- gebd2 (unchanged) ----
  for (int i = 0; i < n; i++){
    {
      float alpha = A[i][i];
      float ssum = 0.f;
      for (int r = i+1; r < n; r++) ssum += A[r][i]*A[r][i];
      float xn = sqrtf(ssum);
      float beta, tv;
      if (n - i <= 1 || xn == 0.f){ tv = 0.f; beta = alpha; }
      else {
        beta = -copysignf(lapy2f(alpha, xn), alpha);
        tv = (beta - alpha)/beta;
        float sc = 1.f/(alpha - beta);
        if (l > i && l < n) A[l][i] *= sc;
      }
      if (l == 0){ d_[i] = beta; tauq[i] = tv; }
      __syncthreads();
      if (tv != 0.f && l > i && l < n){
        int jj = l;
        float w = A[i][jj];
        for (int r = i+1; r < n; r++) w += A[r][i]*A[r][jj];
        w *= tv;
        A[i][jj] -= w;
        for (int r = i+1; r < n; r++) A[r][jj] -= w*A[r][i];
      }
      __syncthreads();
    }
    if (i < n-1){
      float alpha = A[i][i+1];
      float ssum = 0.f;
      for (int c = i+2; c < n; c++) ssum += A[i][c]*A[i][c];
      float xn = sqrtf(ssum);
      float beta, tp;
      if (n - i - 1 <= 1 || xn == 0.f){ tp = 0.f; beta = alpha; }
      else {
        beta = -copysignf(lapy2f(alpha, xn), alpha);
        tp = (beta - alpha)/beta;
        float sc = 1.f/(alpha - beta);
        if (l >= i+2 && l < n) A[i][l] *= sc;
      }
      if (l == 0){ e_[i] = beta; taup[i] = tp; }
      __syncthreads();
      if (tp != 0.f && l > i && l < n){
        int r = l;
        float w = A[r][i+1];
        for (int c = i+2; c < n; c++) w += A[i][c]*A[r][c];
        w *= tp;
        A[r][i+1] -= w;
        for (int c = i+2; c < n; c++) A[r][c] -= w*A[i][c];
      }
      __syncthreads();
    } else {
      if (l == 0) taup[i] = 0.f;
      __syncthreads();
    }
  }
  // ---- bdsqr: all state in registers, wave-uniform control flow ----
  float D[16], E[16], vt[16];
  #pragma unroll
  for (int k = 0; k < 16; k++){
    D[k] = d_[k];
    E[k] = (k < 15) ? e_[k] : 0.f;
    vt[k] = (k == l) ? 1.f : 0.f;
  }
  auto getD = [&](int i)->float{ float r = D[0];
    #pragma unroll
    for (int k = 1; k < 16; k++) if (i == k) r = D[k];
    return r; };
  auto setD = [&](int i, float v){
    #pragma unroll
    for (int k = 0; k < 16; k++) if (i == k) D[k] = v; };
  auto getE = [&](int i)->float{ float r = E[0];
    #pragma unroll
    for (int k = 1; k < 16; k++) if (i == k) r = E[k];
    return r; };
  auto setE = [&](int i, float v){
    #pragma unroll
    for (int k = 0; k < 16; k++) if (i == k) E[k] = v; };
  auto getVt = [&](int i)->float{ float r = vt[0];
    #pragma unroll
    for (int k = 1; k < 16; k++) if (i == k) r = vt[k];
    return r; };
  auto setVt = [&](int i, float v){
    #pragma unroll
    for (int k = 0; k < 16; k++) if (i == k) vt[k] = v; };

  const float eps = 5.9604645e-08f;
  const float unfl = 1.17549435e-38f;
  const float tol = 10.f*eps;
  float sminoa = fabsf(D[0]);
  if (sminoa != 0.f){
    float mu = sminoa;
    #pragma unroll
    for (int i = 1; i < 16; i++){
      mu = fabsf(D[i])*(mu/(mu + fabsf(E[i-1])));
      sminoa = fminf(sminoa, mu);
    }
  }
  sminoa = sminoa / sqrtf((float)n);
  float thresh = fmaxf(tol*sminoa, (float)(6*n*n)*unfl);
  int maxit = 6*n*n;
  int iter = 0, oldll = -1, oldm = -1, mm = n, idir = 0;
  while (true){
    if (mm <= 1) break;
    if (iter > maxit) break;
    float smaxw = fabsf(getD(mm-1));
    int llv = 1; bool split = false;
    {
      bool done = false;
      #pragma unroll
      for (int c = 14; c >= 0; c--){
        if (c <= mm-2 && !done){
          if (fabsf(E[c]) <= thresh){ split = true; llv = c+1; done = true; }
          else smaxw = fmaxf(smaxw, fmaxf(fabsf(D[c]), fabsf(E[c])));
        }
      }
    }
    if (split){
      setE(llv-1, 0.f);
      if (llv == mm-1){ mm = mm - 1; continue; }
      llv = llv + 1;
    }
    if (llv == mm-1){
      float sigmn, sigmx, sinr, cosr, sinl, cosl;
      slasv2_(getD(mm-2), getE(mm-2), getD(mm-1), sigmn, sigmx, sinr, cosr, sinl, cosl);
      setD(mm-2, sigmx); setE(mm-2, 0.f); setD(mm-1, sigmn);
      float t1 = getVt(mm-2), t2 = getVt(mm-1);
      setVt(mm-2, cosr*t1 + sinr*t2);
      setVt(mm-1, cosr*t2 - sinr*t1);
      mm -= 2;
      continue;
    }
    if (llv > oldm || mm < oldll)
      idir = (fabsf(getD(llv-1)) >= fabsf(getD(mm-1))) ? 1 : 2;
    bool deflated = false;
    float sminl = 0.f;
    if (idir == 1){
      if (fabsf(getE(mm-2)) <= tol*fabsf(getD(mm-1))){ setE(mm-2, 0.f); continue; }
      float mu = fabsf(getD(llv-1)); sminl = mu;
      #pragma unroll
      for (int c = 0; c < 15; c++){
        if (c >= llv-1 && c <= mm-2 && !deflated){
          if (fabsf(E[c]) <= tol*mu){ E[c] = 0.f; deflated = true; }
          else {
            mu = fabsf(D[c+1])*(mu/(mu + fabsf(E[c])));
            sminl = fminf(sminl, mu);
          }
        }
      }
    } else {
      if (fabsf(getE(llv-1)) <= tol*fabsf(getD(llv-1))){ setE(llv-1, 0.f); continue; }
      float mu = fabsf(getD(mm-1)); sminl = mu;
      #pragma unroll
      for (int c = 14; c >= 0; c--){
        if (c >= llv-1 && c <= mm-2 && !deflated){
          if (fabsf(E[c]) <= tol*mu){ E[c] = 0.f; deflated = true; }
          else {
            mu = fabsf(D[c])*(mu/(mu + fabsf(E[c])));
            sminl = fminf(sminl, mu);
          }
        }
      }
    }
    if (deflated) continue;
    oldll = llv; oldm = mm;
    float shift = 0.f, rdum;
    if (!((float)n*tol*(sminl/smaxw) <= fmaxf(eps, 0.01f*tol))){
      float sll;
      if (idir == 1){ sll = fabsf(getD(llv-1)); slas2_(getD(mm-2), getE(mm-2), getD(mm-1), shift, rdum); }
      else          { sll = fabsf(getD(mm-1));  slas2_(getD(llv-1), getE(llv-1), getD(llv), shift, rdum); }
      if (sll > 0.f){ float q = shift/sll; if (q*q < eps) shift = 0.f; }
    }
    iter += mm - llv;
    if (shift == 0.f){
      if (idir == 1){
        float cs = 1.f, oldcs = 1.f, sn = 0.f, oldsn = 0.f, rr, dnew;
        #pragma unroll
        for (int i0 = 0; i0 < 15; i0++){
          if (i0 >= llv-1 && i0 <= mm-2){
            slartg_(D[i0]*cs, E[i0], cs, sn, rr);
            if (i0 > llv-1) E[i0-1 < 0 ? 0 : i0-1] = oldsn*rr;
            slartg_(oldcs*rr, D[i0+1]*sn, oldcs, oldsn, dnew);
            D[i0] = dnew;
            if (cs != 1.f || sn != 0.f){
              float t1 = vt[i0], t2 = vt[i0+1];
              vt[i0+1] = cs*t2 - sn*t1;
              vt[i0]   = sn*t2 + cs*t1;
            }
          }
        }
        float h = getD(mm-1)*cs;
        setD(mm-1, h*oldcs);
        float hv = h*oldsn;
        setE(mm-2, (fabsf(hv) <= thresh) ? 0.f : hv);
      } else {
        float cs = 1.f, oldcs = 1.f, sn = 0.f, oldsn = 0.f, rr, dnew;
        #pragma unroll
        for (int i0 = 15; i0 >= 1; i0--){
          if (i0 >= llv && i0 <= mm-1){
            slartg_(D[i0]*cs, E[i0-1], cs, sn, rr);
            if (i0 < mm-1) E[i0] = oldsn*rr;
            slartg_(oldcs*rr, D[i0-1]*sn, oldcs, oldsn, dnew);
            D[i0] = dnew;
            float cR = oldcs, sR = -oldsn;
            if (cR != 1.f || sR != 0.f){
              float t1 = vt[i0-1], t2 = vt[i0];
              vt[i0]   = cR*t2 - sR*t1;
              vt[i0-1] = sR*t2 + cR*t1;
            }
          }
        }
        float h = getD(llv-1)*cs;
        setD(llv-1, h*oldcs);
        float hv = h*oldsn;
        setE(llv-1, (fabsf(hv) <= thresh) ? 0.f : hv);
      }
    } else {
      if (idir == 1){
        float dl = getD(llv-1);
        float ff = (fabsf(dl) - shift)*(copysignf(1.f, dl) + shift/dl);
        float gg = getE(llv-1);
        float cosr, sinr, cosl, sinl, rr;
        #pragma unroll
        for (int i0 = 0; i0 < 15; i0++){
          if (i0 >= llv-1 && i0 <= mm-2){
            slartg_(ff, gg, cosr, sinr, rr);
            if (i0 > llv-1) E[i0-1 < 0 ? 0 : i0-1] = rr;
            float di = D[i0], ei = E[i0];
            ff = cosr*di + sinr*ei;
            E[i0] = cosr*ei - sinr*di;
            gg = sinr*D[i0+1];
            D[i0+1] = cosr*D[i0+1];
            slartg_(ff, gg, cosl, sinl, rr);
            D[i0] = rr;
            float ei2 = E[i0], dip = D[i0+1];
            ff = cosl*ei2 + sinl*dip;
            D[i0+1] = cosl*dip - sinl*ei2;
            if (i0 < mm-2){
              gg = sinl*E[i0+1];
              E[i0+1] = cosl*E[i0+1];
            }
            if (cosr != 1.f || sinr != 0.f){
              float t1 = vt[i0], t2 = vt[i0+1];
              vt[i0+1] = cosr*t2 - sinr*t1;
              vt[i0]   = sinr*t2 + cosr*t1;
            }
          }
        }
        setE(mm-2, (fabsf(ff) <= thresh) ? 0.f : ff);
      } else {
        float dm = getD(mm-1);
        float ff = (fabsf(dm) - shift)*(copysignf(1.f, dm) + shift/dm);
        float gg = getE(mm-2);
        float cosr, sinr, cosl, sinl, rr;
        #pragma unroll
        for (int i0 = 15; i0 >= 1; i0--){
          if (i0 >= llv && i0 <= mm-1){
            slartg_(ff, gg, cosr, sinr, rr);
            if (i0 < mm-1) E[i0] = rr;
            float di = D[i0], eim = E[i0-1];
            ff = cosr*di + sinr*eim;
            E[i0-1] = cosr*eim - sinr*di;
            gg = sinr*D[i0-1];
            D[i0-1] = cosr*D[i0-1];
            slartg_(ff, gg, cosl, sinl, rr);
            D[i0] = rr;
            float eim2 = E[i0-1], dim = D[i0-1];
            ff = cosl*eim2 + sinl*dim;
            D[i0-1] = cosl*dim - sinl*eim2;
            if (i0 > llv){
              gg = sinl*E[i0-2 < 0 ? 0 : i0-2];
              E[i0-2 < 0 ? 0 : i0-2] = cosl*E[i0-2 < 0 ? 0 : i0-2];
            }
            float cR = cosr, sR = -sinr;
            if (cR != 1.f || sR != 0.f){
              float t1 = vt[i0-1], t2 = vt[i0];
              vt[i0]   = cR*t2 - sR*t1;
              vt[i0-1] = sR*t2 + cR*t1;
            }
          }
        }
        setE(llv-1, (fabsf(ff) <= thresh) ? 0.f : ff);
      }
    }
  }
  // make positive
  #pragma unroll
  for (int k = 0; k < 16; k++){
    if (D[k] < 0.f){ D[k] = -D[k]; vt[k] = -vt[k]; }
  }
  // sort decreasing (selection, same tie-breaks as LAPACK slasrt-path in bdsqr)
  #pragma unroll
  for (int i = 1; i <= 15; i++){
    int isub = 1; float smn = D[0];
    #pragma unroll
    for (int jj = 2; jj <= 16; jj++){
      if (jj <= 16 + 1 - i){
        if (D[jj-1] <= smn){ isub = jj; smn = D[jj-1]; }
      }
    }
    if (isub != 16 + 1 - i){
      setD(isub - 1, D[16 - i]);
      D[16 - i] = smn;
      float tmp = getVt(isub - 1);
      setVt(isub - 1, vt[16 - i]);
      vt[16 - i] = tmp;
    }
  }
  // dump VT to LDS for row-wise ormbr
  if (l < 16){
    #pragma unroll
    for (int r = 0; r < 16; r++) VTm[r][l] = vt[r];
  }
  __syncthreads();
  // ormbr('P','R','T'): VT := VT * G(n-1)...G(1)
  for (int i = n-2; i >= 0; i--){
    float tp = taup[i];
    if (tp != 0.f && l < 16){
      int r = l;
      float w = VTm[r][i+1];
      for (int c = i+2; c < n; c++) w += VTm[r][c]*A[i][c];
      w *= tp;
      VTm[r][i+1] -= w;
      for (int c = i+2; c < n; c++) VTm[r][c] -= w*A[i][c];
    }
    __syncthreads();
  }
  for (int idx = l; idx < 256; idx += 64) vtlOut[idx] = VTm[idx>>4][idx&15];
}

// K12: R = Qqr * VT_L^T ; Rinv = R^T
__global__ __launch_bounds__(256) void k_rout(float* __restrict__ ws, float* __restrict__ out){
  int ty = blockIdx.y;
  const float* Qq = ws + OFF_QQR + (size_t)ty*65536;
  const float* vtl = ws + OFF_VTL + ty*256;
  long long Roff  = ty ? OUT_R2  : OUT_R1;
  long long RIoff = ty ? OUT_RI2 : OUT_RI1;
  __shared__ float V[16][16];
  int t = threadIdx.x;
  V[t>>4][t&15] = vtl[t];
  __syncthreads();
  int row = blockIdx.x*256 + t;
  float mv[16];
  #pragma unroll
  for (int q = 0; q < 4; q++){
    float4 v = ((const float4*)(Qq + (size_t)row*16))[q];
    mv[q*4] = v.x; mv[q*4+1] = v.y; mv[q*4+2] = v.z; mv[q*4+3] = v.w;
  }
  #pragma unroll
  for (int j = 0; j < 16; j++){
    float s = 0.f;
    #pragma unroll
    for (int i = 0; i < 16; i++) s = fmaf(mv[i], V[j][i], s);
    out[Roff + (long long)row*16 + j] = s;
    out[RIoff + (long long)j*4096 + row] = s;
  }
}

// ===========================================================================
extern "C" void kernel_launch(void* const* d_in, const int* in_sizes, int n_in,
                              void* d_out, int out_size, void* d_ws, size_t ws_size,
                              hipStream_t stream){
  const float* x1 = (const float*)d_in[0];
  const float* x2 = (const float*)d_in[1];
  float* out = (float*)d_out;
  float* ws = (float*)d_ws;
  (void)in_sizes; (void)n_in; (void)out_size; (void)ws_size;

  hipMemsetAsync(d_ws, 0, ZERO_FLOATS*sizeof(float), stream);

  k_hadamard_hist<<<dim3(512), 256, 0, stream>>>(x1, x2, out, ws);
  k_coarse_red<<<dim3(16, 2), 256, 0, stream>>>(ws);
  k_coarse_scan<<<dim3(2), 256, 0, stream>>>(ws);
  k_fine_fb<<<dim3(1024, 2), 256, 0, stream>>>(x1, x2, ws);
  k_seg_sum<<<dim3(1024, 2), 256, 0, stream>>>(ws);
  k_fine_scan2<<<dim3(2), 256, 0, stream>>>(ws, out);

  uint32_t a0, a1, b0, b1;
  h_threefry(0u, 42u, 0u, 0u, a0, a1);
  h_threefry(0u, 42u, 0u, 1u, b0, b1);
  k_omega<<<dim3(256, 2), 256, 0, stream>>>(a0, a1, b0, b1, ws);

  // QR1
  k_atype<<<dim3(512, 2), 256, 0, stream>>>(x1, x2, ws, OFF_OMT);
  k_gramP<<<dim3(64, 2), 256, 0, stream>>>(ws, OFF_BIGY, 131072);
  k_tiny<<<dim3(2), 64, 0, stream>>>(ws, OFF_BIGY, 131072);
  k_applyq<<<dim3(32, 2), 256, 0, stream>>>(ws, OFF_BIGY, 131072, OFF_BIGQ, 131072, 8192, 1, 0);
  // QR2
  k_btype<<<dim3(256, 2), 256, 0, stream>>>(x1, x2, ws);
  k_bredgram<<<dim3(64, 2), 256, 0, stream>>>(ws);
  k_tiny<<<dim3(2), 64, 0, stream>>>(ws, OFF_TMAT, 65536);
  k_applyq<<<dim3(16, 2), 256, 0, stream>>>(ws, OFF_TMAT, 65536, OFF_ZT, 65536, 4096, 0, 1);
  // QR3
  k_atype<<<dim3(512, 2), 256, 0, stream>>>(x1, x2, ws, OFF_ZT);
  k_gramP<<<dim3(64, 2), 256, 0, stream>>>(ws, OFF_BIGY, 131072);
  k_tiny<<<dim3(2), 64, 0, stream>>>(ws, OFF_BIGY, 131072);
  k_applyq<<<dim3(32, 2), 256, 0, stream>>>(ws, OFF_BIGY, 131072, OFF_BIGQ, 131072, 8192, 1, 0);
  // QR4
  k_btype<<<dim3(256, 2), 256, 0, stream>>>(x1, x2, ws);
  k_bredgram<<<dim3(64, 2), 256, 0, stream>>>(ws);
  k_tiny<<<dim3(2), 64, 0, stream>>>(ws, OFF_TMAT, 65536);
  k_applyq<<<dim3(16, 2), 256, 0, stream>>>(ws, OFF_TMAT, 65536, OFF_ZT, 65536, 4096, 0, 1);
  // QR5
  k_atype<<<dim3(512, 2), 256, 0, stream>>>(x1, x2, ws, OFF_ZT);
  k_gramP<<<dim3(64, 2), 256, 0, stream>>>(ws, OFF_BIGY, 131072);
  k_tiny<<<dim3(2), 64, 0, stream>>>(ws, OFF_BIGY, 131072);
  k_applyq<<<dim3(32, 2), 256, 0, stream>>>(ws, OFF_BIGY, 131072, OFF_BIGQ, 131072, 8192, 1, 0);
  // QR6
  k_btype<<<dim3(256, 2), 256, 0, stream>>>(x1, x2, ws);
  k_bredgram<<<dim3(64, 2), 256, 0, stream>>>(ws);
  k_tiny<<<dim3(2), 64, 0, stream>>>(ws, OFF_TMAT, 65536);
  k_applyq<<<dim3(16, 2), 256, 0, stream>>>(ws, OFF_TMAT, 65536, OFF_QQR, 65536, 4096, 1, 0);

  k_chain<<<dim3(2), 64, 0, stream>>>(ws);
  k_rout<<<dim3(16, 2), 256, 0, stream>>>(ws, out);
}